// Round 9
// baseline (1140.453 us; speedup 1.0000x reference)
//
#include <hip/hip_runtime.h>

#define NN 50000
#define NE 400000
#define NBATCH 8
#define DD 128
#define EGRID 512
#define ETILES 6250
#define NGRID 512
#define NTILES 782

typedef unsigned short u16;
typedef __attribute__((ext_vector_type(8))) short bf16x8;
typedef __attribute__((ext_vector_type(8))) unsigned short u16x8;
typedef __attribute__((ext_vector_type(4))) unsigned short u16x4;
typedef __attribute__((ext_vector_type(4))) float f32x4;

__device__ __forceinline__ u16 f2bf(float f) {
  union { float f; unsigned u; } a; a.f = f;
  unsigned r = a.u + 0x7fffu + ((a.u >> 16) & 1u);
  return (u16)(r >> 16);
}

__device__ __forceinline__ void glds16(const void* g, void* l) {
  __builtin_amdgcn_global_load_lds(
      (const __attribute__((address_space(1))) unsigned*)g,
      (__attribute__((address_space(3))) unsigned*)l, 16, 0, 0);
}

// Convert+transpose fp32 weight [K][128] -> bf16 chunked [K/128][128 n][128 k]
__global__ void wconv_kernel(const float* __restrict__ src, u16* __restrict__ dst, int K) {
  int idx = blockIdx.x * 256 + threadIdx.x;
  if (idx >= K * 128) return;
  int k = idx >> 7, n = idx & 127;
  dst[((k >> 7) << 14) + (n << 7) + (k & 127)] = f2bf(src[idx]);
}

__global__ void xconv_kernel(const float* __restrict__ x, u16* __restrict__ xbf, int total4) {
  int i = blockIdx.x * 256 + threadIdx.x;
  if (i >= total4) return;
  f32x4 v = ((const f32x4*)x)[i];
  u16x4 o; o[0]=f2bf(v[0]); o[1]=f2bf(v[1]); o[2]=f2bf(v[2]); o[3]=f2bf(v[3]);
  ((u16x4*)xbf)[i] = o;
}

__global__ void nhist_kernel(const int* __restrict__ batch, unsigned* __restrict__ ncnt) {
  __shared__ unsigned h[NBATCH];
  if (threadIdx.x < NBATCH) h[threadIdx.x] = 0;
  __syncthreads();
  int i = blockIdx.x * 256 + threadIdx.x;
  if (i < NN) atomicAdd(&h[batch[i]], 1u);
  __syncthreads();
  if (threadIdx.x < NBATCH) atomicAdd(&ncnt[threadIdx.x], h[threadIdx.x]);
}

__global__ void ecnt_kernel(const int* __restrict__ edge_index, const int* __restrict__ batch,
                            unsigned* __restrict__ ecnt) {
  __shared__ unsigned h[NBATCH];
  if (threadIdx.x < NBATCH) h[threadIdx.x] = 0;
  __syncthreads();
  int e = blockIdx.x * 256 + threadIdx.x;
  if (e < NE) atomicAdd(&h[batch[edge_index[e]]], 1u);
  __syncthreads();
  if (threadIdx.x < NBATCH) atomicAdd(&ecnt[threadIdx.x], h[threadIdx.x]);
}

// sum per-block partials [nblk][1024] -> out[1024]
__global__ void partred_kernel(const float* __restrict__ part, float* __restrict__ out, int nblk) {
  int i = blockIdx.x * 256 + threadIdx.x;
  if (i >= NBATCH * 128) return;
  float s = 0.f;
  for (int b = 0; b < nblk; ++b) s += part[(size_t)b * 1024 + i];
  out[i] = s;
}

// ---- shared compute macros (A from LDS, B from registers / global) ----
#define COMPUTE_REG(BUF, WF, CBASE) do {                                          \
  _Pragma("unroll")                                                               \
  for (int kk = 0; kk < 4; ++kk) {                                                \
    bf16x8 af_[4];                                                                \
    _Pragma("unroll")                                                             \
    for (int m = 0; m < 4; ++m) {                                                 \
      int g_ = m * 16 + lr;                                                       \
      int slot_ = kk * 4 + lkb;                                                   \
      af_[m] = *(const bf16x8*)((BUF) + g_ * 128 + ((slot_ ^ (g_ & 7)) << 3));    \
    }                                                                             \
    _Pragma("unroll")                                                             \
    for (int m = 0; m < 4; ++m) {                                                 \
      acc[m][0] = __builtin_amdgcn_mfma_f32_16x16x32_bf16(af_[m], WF[(CBASE)*4+kk][0], acc[m][0], 0,0,0); \
      acc[m][1] = __builtin_amdgcn_mfma_f32_16x16x32_bf16(af_[m], WF[(CBASE)*4+kk][1], acc[m][1], 0,0,0); \
    }                                                                             \
  }                                                                               \
} while (0)

#define COMPUTE_GLB(BUF, W) do {                                                  \
  _Pragma("unroll")                                                               \
  for (int kk = 0; kk < 4; ++kk) {                                                \
    const int k0_ = kk * 32 + lkb * 8;                                            \
    bf16x8 af_[4], bv_[2];                                                        \
    _Pragma("unroll")                                                             \
    for (int m = 0; m < 4; ++m) {                                                 \
      int g_ = m * 16 + lr;                                                       \
      int slot_ = kk * 4 + lkb;                                                   \
      af_[m] = *(const bf16x8*)((BUF) + g_ * 128 + ((slot_ ^ (g_ & 7)) << 3));    \
    }                                                                             \
    _Pragma("unroll")                                                             \
    for (int n = 0; n < 2; ++n)                                                   \
      bv_[n] = *(const bf16x8*)((W) + ((wc * 32 + n * 16 + lr) << 7) + k0_);      \
    _Pragma("unroll")                                                             \
    for (int m = 0; m < 4; ++m) {                                                 \
      acc[m][0] = __builtin_amdgcn_mfma_f32_16x16x32_bf16(af_[m], bv_[0], acc[m][0], 0,0,0); \
      acc[m][1] = __builtin_amdgcn_mfma_f32_16x16x32_bf16(af_[m], bv_[1], acc[m][1], 0,0,0); \
    }                                                                             \
  }                                                                               \
} while (0)

#define EPI_RELU(HS, BV) do {                                                     \
  _Pragma("unroll")                                                               \
  for (int n = 0; n < 2; ++n) {                                                   \
    int colg_ = wc * 32 + n * 16 + lr;                                            \
    int slot_ = colg_ >> 3;                                                       \
    _Pragma("unroll")                                                             \
    for (int m = 0; m < 4; ++m)                                                   \
      _Pragma("unroll")                                                           \
      for (int r = 0; r < 4; ++r) {                                               \
        int rowg_ = m * 16 + lkb * 4 + r;                                         \
        float v_ = fmaxf(acc[m][n][r] + BV[n], 0.f);                              \
        (HS)[rowg_ * 128 + ((slot_ ^ (rowg_ & 7)) << 3) + (colg_ & 7)] = f2bf(v_);\
        acc[m][n][r] = 0.f;                                                       \
      }                                                                           \
  }                                                                               \
} while (0)

// ---------------- Edge MLP: persistent, w1/w2 in registers ----------------
__global__ __launch_bounds__(256, 2) void edge_kernel(
    const u16* __restrict__ xbf, const u16* __restrict__ eabf /*may be null*/,
    const float* __restrict__ ea_f32, const u16* __restrict__ ubf,
    const int* __restrict__ edge_index, const int* __restrict__ batch,
    const u16* __restrict__ w1, const u16* __restrict__ w2, const u16* __restrict__ w3,
    const float* __restrict__ b1, const float* __restrict__ b2, const float* __restrict__ b3,
    float* __restrict__ edge_out, float* agg, float* __restrict__ esumPart)
{
  __shared__ u16 A0[64 * 128], A1[64 * 128], A2[64 * 128];   // 48 KB
  __shared__ float red[NBATCH * 128];
  __shared__ int rows_s[2][64], cols_s[2][64], ebat_s[2][64];

  const int tid  = threadIdx.x;
  const int lane = tid & 63;
  const int wave = tid >> 6;
  const int wc   = wave;
  const int lr   = lane & 15;
  const int lkb  = lane >> 4;
  const int bid  = blockIdx.x;
  const int ntiles = (ETILES - bid + EGRID - 1) / EGRID;

  // ---- load weight fragments to registers (once)
  bf16x8 w1f[16][2], w2f[4][2];
#pragma unroll
  for (int c = 0; c < 4; ++c)
#pragma unroll
    for (int kk = 0; kk < 4; ++kk)
#pragma unroll
      for (int n = 0; n < 2; ++n)
        w1f[c * 4 + kk][n] = *(const bf16x8*)(w1 + (c << 14) + ((wc * 32 + n * 16 + lr) << 7) + kk * 32 + lkb * 8);
#pragma unroll
  for (int kk = 0; kk < 4; ++kk)
#pragma unroll
    for (int n = 0; n < 2; ++n)
      w2f[kk][n] = *(const bf16x8*)(w2 + ((wc * 32 + n * 16 + lr) << 7) + kk * 32 + lkb * 8);

  float b1v[2], b2v[2], b3v[2];
#pragma unroll
  for (int n = 0; n < 2; ++n) {
    b1v[n] = b1[wc * 32 + n * 16 + lr];
    b2v[n] = b2[wc * 32 + n * 16 + lr];
    b3v[n] = b3[wc * 32 + n * 16 + lr];
  }

  f32x4 acc[4][2];
#pragma unroll
  for (int m = 0; m < 4; ++m)
#pragma unroll
    for (int n = 0; n < 2; ++n) { acc[m][n][0]=0.f; acc[m][n][1]=0.f; acc[m][n][2]=0.f; acc[m][n][3]=0.f; }

  for (int i = tid; i < NBATCH * 128; i += 256) red[i] = 0.f;

  // stage chunk c of the tile whose indices live in parity slot p
  auto stage = [&](u16* buf, int c, int p, int e0) {
    if (c == 2 && eabf == nullptr) {
#pragma unroll
      for (int j = 0; j < 4; ++j) {
        int idx = j * 64 + lane;
        int rr = wave * 16 + (idx >> 4);
        int k  = idx & 15;
        const float* ptr = ea_f32 + (size_t)(e0 + rr) * DD + k * 8;
        f32x4 a = *(const f32x4*)ptr;
        f32x4 b = *(const f32x4*)(ptr + 4);
        u16x8 v;
        v[0]=f2bf(a[0]); v[1]=f2bf(a[1]); v[2]=f2bf(a[2]); v[3]=f2bf(a[3]);
        v[4]=f2bf(b[0]); v[5]=f2bf(b[1]); v[6]=f2bf(b[2]); v[7]=f2bf(b[3]);
        *(u16x8*)&buf[rr * 128 + ((k ^ (rr & 7)) << 3)] = v;
      }
      return;
    }
#pragma unroll
    for (int i = 0; i < 4; ++i) {
      int rr = wave * 16 + i * 4 + (lane >> 4);
      const u16* rp;
      if (c == 0)      rp = xbf + (size_t)rows_s[p][rr] * DD;
      else if (c == 1) rp = xbf + (size_t)cols_s[p][rr] * DD;
      else if (c == 2) rp = eabf + (size_t)(e0 + rr) * DD;
      else             rp = ubf + (size_t)ebat_s[p][rr] * DD;
      const u16* src = rp + (((lane & 15) ^ (rr & 7)) << 3);
      u16* dst = &buf[(wave * 16 + i * 4) * 128];
      glds16(src, dst);
    }
  };

  // prologue: indices for tile 0 -> slot 0, then stage c0 -> A2
  {
    int e0 = bid * 64;
    if (tid < 64) {
      int r = edge_index[e0 + tid];
      int cc = edge_index[NE + e0 + tid];
      rows_s[0][tid] = r; cols_s[0][tid] = cc; ebat_s[0][tid] = batch[r];
    }
  }
  __syncthreads();
  stage(A2, 0, 0, bid * 64);
  __syncthreads();

  for (int k = 0; k < ntiles; ++k) {
    const int p  = k & 1;
    const int e0 = (bid + k * EGRID) * 64;
    const bool hasNext = (k + 1 < ntiles);
    const int e0n = hasNext ? (bid + (k + 1) * EGRID) * 64 : e0;
    const int pn  = hasNext ? (p ^ 1) : p;

    // prefetch next tile's indices into the other parity slot
    if (hasNext && tid < 64) {
      int r = edge_index[e0n + tid];
      int cc = edge_index[NE + e0n + tid];
      rows_s[p ^ 1][tid] = r; cols_s[p ^ 1][tid] = cc; ebat_s[p ^ 1][tid] = batch[r];
    }

    stage(A0, 1, p, e0); COMPUTE_REG(A2, w1f, 0); __syncthreads();
    stage(A1, 2, p, e0); COMPUTE_REG(A0, w1f, 1); __syncthreads();
    stage(A0, 3, p, e0); COMPUTE_REG(A1, w1f, 2); __syncthreads();
    COMPUTE_REG(A0, w1f, 3);
    EPI_RELU(A1, b1v);
    __syncthreads();
    COMPUTE_REG(A1, w2f, 0);
    EPI_RELU(A0, b2v);
    __syncthreads();
    stage(A2, 0, pn, e0n);
    COMPUTE_GLB(A0, w3);

    // epilogue: edge_out stores + agg scatter atomics + per-graph red (LDS)
#pragma unroll
    for (int n = 0; n < 2; ++n) {
      int colg = wc * 32 + n * 16 + lr;
#pragma unroll
      for (int m = 0; m < 4; ++m)
#pragma unroll
        for (int r = 0; r < 4; ++r) {
          int rowg = m * 16 + lkb * 4 + r;
          float v = acc[m][n][r] + b3v[n];
          edge_out[(size_t)(e0 + rowg) * DD + colg] = v;
          atomicAdd(&agg[(size_t)cols_s[p][rowg] * DD + colg], v);
          atomicAdd(&red[ebat_s[p][rowg] * 128 + colg], v);
          acc[m][n][r] = 0.f;
        }
    }
    __syncthreads();   // drains A2 glds + makes idx prefetch visible + red done
  }

  // flush per-block esum partial (plain stores, no contention)
  for (int i = tid; i < NBATCH * 128; i += 256)
    esumPart[(size_t)bid * 1024 + i] = red[i];
}

// ---------------- Node MLP: persistent, n1/n2 in registers ----------------
__global__ __launch_bounds__(256, 2) void node_kernel(
    const u16* __restrict__ xbf, const float* __restrict__ aggsrc, float* __restrict__ x_out,
    const u16* __restrict__ ubf, const int* __restrict__ batch,
    const u16* __restrict__ w1, const u16* __restrict__ w2, const u16* __restrict__ w3,
    const float* __restrict__ b1, const float* __restrict__ b2, const float* __restrict__ b3,
    float* __restrict__ nsumPart)
{
  __shared__ u16 A0[64 * 128], A1[64 * 128], A2[64 * 128];
  __shared__ float red[NBATCH * 128];
  __shared__ int nbat_s[2][64];

  const int tid  = threadIdx.x;
  const int lane = tid & 63;
  const int wave = tid >> 6;
  const int wc   = wave;
  const int lr   = lane & 15;
  const int lkb  = lane >> 4;
  const int bid  = blockIdx.x;
  const int ntiles = (NTILES - bid + NGRID - 1) / NGRID;

  bf16x8 n1f[12][2], n2f[4][2];
#pragma unroll
  for (int c = 0; c < 3; ++c)
#pragma unroll
    for (int kk = 0; kk < 4; ++kk)
#pragma unroll
      for (int n = 0; n < 2; ++n)
        n1f[c * 4 + kk][n] = *(const bf16x8*)(w1 + (c << 14) + ((wc * 32 + n * 16 + lr) << 7) + kk * 32 + lkb * 8);
#pragma unroll
  for (int kk = 0; kk < 4; ++kk)
#pragma unroll
    for (int n = 0; n < 2; ++n)
      n2f[kk][n] = *(const bf16x8*)(w2 + ((wc * 32 + n * 16 + lr) << 7) + kk * 32 + lkb * 8);

  float b1v[2], b2v[2], b3v[2];
#pragma unroll
  for (int n = 0; n < 2; ++n) {
    b1v[n] = b1[wc * 32 + n * 16 + lr];
    b2v[n] = b2[wc * 32 + n * 16 + lr];
    b3v[n] = b3[wc * 32 + n * 16 + lr];
  }

  f32x4 acc[4][2];
#pragma unroll
  for (int m = 0; m < 4; ++m)
#pragma unroll
    for (int n = 0; n < 2; ++n) { acc[m][n][0]=0.f; acc[m][n][1]=0.f; acc[m][n][2]=0.f; acc[m][n][3]=0.f; }

  for (int i = tid; i < NBATCH * 128; i += 256) red[i] = 0.f;

  auto stage_x = [&](u16* buf, int n0) {       // chunk 0: xbf rows (glds)
#pragma unroll
    for (int i = 0; i < 4; ++i) {
      int rr = wave * 16 + i * 4 + (lane >> 4);
      int node = n0 + rr; if (node >= NN) node = 0;
      const u16* src = xbf + (size_t)node * DD + (((lane & 15) ^ (rr & 7)) << 3);
      glds16(src, &buf[(wave * 16 + i * 4) * 128]);
    }
  };
  auto stage_u = [&](u16* buf, int p) {        // chunk 2: ubf rows (glds)
#pragma unroll
    for (int i = 0; i < 4; ++i) {
      int rr = wave * 16 + i * 4 + (lane >> 4);
      const u16* src = ubf + (size_t)nbat_s[p][rr] * DD + (((lane & 15) ^ (rr & 7)) << 3);
      glds16(src, &buf[(wave * 16 + i * 4) * 128]);
    }
  };
  auto stage_agg = [&](u16* buf, int n0) {     // chunk 1: agg fp32 -> bf16
#pragma unroll
    for (int j = 0; j < 4; ++j) {
      int idx = j * 64 + lane;
      int rr = wave * 16 + (idx >> 4);
      int k  = idx & 15;
      int node = n0 + rr; if (node >= NN) node = 0;
      const float* ptr = aggsrc + (size_t)node * DD + k * 8;
      f32x4 a = *(const f32x4*)ptr;
      f32x4 b = *(const f32x4*)(ptr + 4);
      u16x8 v;
      v[0]=f2bf(a[0]); v[1]=f2bf(a[1]); v[2]=f2bf(a[2]); v[3]=f2bf(a[3]);
      v[4]=f2bf(b[0]); v[5]=f2bf(b[1]); v[6]=f2bf(b[2]); v[7]=f2bf(b[3]);
      *(u16x8*)&buf[rr * 128 + ((k ^ (rr & 7)) << 3)] = v;
    }
  };

  {
    int n0 = bid * 64;
    if (tid < 64) {
      int node = n0 + tid;
      nbat_s[0][tid] = (node < NN) ? batch[node] : 0;
    }
  }
  __syncthreads();
  stage_x(A2, bid * 64);
  __syncthreads();

  for (int k = 0; k < ntiles; ++k) {
    const int p  = k & 1;
    const int n0 = (bid + k * NGRID) * 64;
    const bool hasNext = (k + 1 < ntiles);
    const int n0n = hasNext ? (bid + (k + 1) * NGRID) * 64 : n0;

    if (hasNext && tid < 64) {
      int node = n0n + tid;
      nbat_s[p ^ 1][tid] = (node < NN) ? batch[node] : 0;
    }

    stage_agg(A0, n0); COMPUTE_REG(A2, n1f, 0); __syncthreads();
    stage_u(A1, p);    COMPUTE_REG(A0, n1f, 1); __syncthreads();
    COMPUTE_REG(A1, n1f, 2);
    EPI_RELU(A0, b1v);
    __syncthreads();
    COMPUTE_REG(A0, n2f, 0);
    EPI_RELU(A1, b2v);
    __syncthreads();
    stage_x(A2, n0n);
    COMPUTE_GLB(A1, w3);

#pragma unroll
    for (int n = 0; n < 2; ++n) {
      int colg = wc * 32 + n * 16 + lr;
#pragma unroll
      for (int m = 0; m < 4; ++m)
#pragma unroll
        for (int r = 0; r < 4; ++r) {
          int rowg = m * 16 + lkb * 4 + r;
          int node = n0 + rowg;
          float v = acc[m][n][r] + b3v[n];
          if (node < NN) {
            x_out[(size_t)node * DD + colg] = v;
            atomicAdd(&red[nbat_s[p][rowg] * 128 + colg], v);
          }
          acc[m][n][r] = 0.f;
        }
    }
    __syncthreads();
  }

  for (int i = tid; i < NBATCH * 128; i += 256)
    nsumPart[(size_t)bid * 1024 + i] = red[i];
}

// ---------------- Global MLP (fp32, tiny) ----------------
__global__ void global_kernel(
    const float* __restrict__ u,
    const float* __restrict__ nsum, const unsigned* __restrict__ ncnt,
    const float* __restrict__ esum, const unsigned* __restrict__ ecnt,
    const float* __restrict__ gW1, const float* __restrict__ gb1,
    const float* __restrict__ gW2, const float* __restrict__ gb2,
    const float* __restrict__ gW3, const float* __restrict__ gb3,
    float* __restrict__ u_out)
{
  __shared__ float gin[NBATCH][384];
  __shared__ float h1[NBATCH][128];
  __shared__ float h2[NBATCH][128];
  int tid = threadIdx.x;
  for (int i = tid; i < NBATCH * 128; i += 256) {
    int r = i >> 7, c = i & 127;
    float nc = (float)(ncnt[r] < 1u ? 1u : ncnt[r]);
    float ec = (float)(ecnt[r] < 1u ? 1u : ecnt[r]);
    gin[r][c] = u[i];
    gin[r][128 + c] = nsum[i] / nc;
    gin[r][256 + c] = esum[i] / ec;
  }
  __syncthreads();
  for (int o = tid; o < NBATCH * 128; o += 256) {
    int r = o >> 7, n = o & 127;
    float s = gb1[n];
    for (int k = 0; k < 384; ++k) s += gin[r][k] * gW1[k * 128 + n];
    h1[r][n] = fmaxf(s, 0.f);
  }
  __syncthreads();
  for (int o = tid; o < NBATCH * 128; o += 256) {
    int r = o >> 7, n = o & 127;
    float s = gb2[n];
    for (int k = 0; k < 128; ++k) s += h1[r][k] * gW2[k * 128 + n];
    h2[r][n] = fmaxf(s, 0.f);
  }
  __syncthreads();
  for (int o = tid; o < NBATCH * 128; o += 256) {
    int r = o >> 7, n = o & 127;
    float s = gb3[n];
    for (int k = 0; k < 128; ++k) s += h2[r][k] * gW3[k * 128 + n];
    u_out[o] = s;
  }
}

extern "C" void kernel_launch(void* const* d_in, const int* in_sizes, int n_in,
                              void* d_out, int out_size, void* d_ws, size_t ws_size,
                              hipStream_t stream) {
  const float* x          = (const float*)d_in[0];
  const int*   edge_index = (const int*)d_in[1];
  const float* edge_attr  = (const float*)d_in[2];
  const float* u          = (const float*)d_in[3];
  const int*   batch      = (const int*)d_in[4];
  const float* eW1 = (const float*)d_in[5];  const float* eb1 = (const float*)d_in[6];
  const float* eW2 = (const float*)d_in[7];  const float* eb2 = (const float*)d_in[8];
  const float* eW3 = (const float*)d_in[9];  const float* eb3 = (const float*)d_in[10];
  const float* nW1 = (const float*)d_in[11]; const float* nb1 = (const float*)d_in[12];
  const float* nW2 = (const float*)d_in[13]; const float* nb2 = (const float*)d_in[14];
  const float* nW3 = (const float*)d_in[15]; const float* nb3 = (const float*)d_in[16];
  const float* gW1 = (const float*)d_in[17]; const float* gb1 = (const float*)d_in[18];
  const float* gW2 = (const float*)d_in[19]; const float* gb2 = (const float*)d_in[20];
  const float* gW3 = (const float*)d_in[21]; const float* gb3 = (const float*)d_in[22];

  float* out      = (float*)d_out;
  float* xout_agg = out;                                  // [NN][128]: agg then x_out
  float* edge_out = out + (size_t)NN * DD;                // [NE][128]
  float* u_out    = out + (size_t)(NN + NE) * DD;         // [8][128]

  char* ws = (char*)d_ws;
  u16* wE1t = (u16*)(ws + 0);         // 131072
  u16* wE2t = (u16*)(ws + 131072);    // 32768
  u16* wE3t = (u16*)(ws + 163840);    // 32768
  u16* wN1t = (u16*)(ws + 196608);    // 98304
  u16* wN2t = (u16*)(ws + 294912);    // 32768
  u16* wN3t = (u16*)(ws + 327680);    // 32768
  float*    esum = (float*)(ws + 360448);     // 4096
  float*    nsum = (float*)(ws + 364544);     // 4096
  unsigned* ecnt = (unsigned*)(ws + 368640);  // 32
  unsigned* ncnt = (unsigned*)(ws + 368672);  // 32
  u16*      ubf  = (u16*)(ws + 369664);       // 2048
  u16*      xbf  = (u16*)(ws + 393216);       // 12,800,000 -> ends 13,193,216
  float* esumPart = (float*)(ws + 13193216);  // 512*1024*4 = 2,097,152
  float* nsumPart = (float*)(ws + 15290368);  // 2,097,152 -> ends 17,387,520
  const size_t EABF_OFF = 17391616;
  const size_t EABF_END = EABF_OFF + (size_t)NE * DD * 2; // 119,791,616
  u16* eabf = (ws_size >= EABF_END) ? (u16*)(ws + EABF_OFF) : nullptr;

  // zero agg region (x_out part of d_out) and count accumulators
  hipMemsetAsync(d_out, 0, (size_t)NN * DD * sizeof(float), stream);
  hipMemsetAsync(ws + 368640, 0, 64, stream);

  wconv_kernel<<<256, 256, 0, stream>>>(eW1, wE1t, 512);
  wconv_kernel<<<64, 256, 0, stream>>>(eW2, wE2t, 128);
  wconv_kernel<<<64, 256, 0, stream>>>(eW3, wE3t, 128);
  wconv_kernel<<<192, 256, 0, stream>>>(nW1, wN1t, 384);
  wconv_kernel<<<64, 256, 0, stream>>>(nW2, wN2t, 128);
  wconv_kernel<<<64, 256, 0, stream>>>(nW3, wN3t, 128);
  xconv_kernel<<<6250, 256, 0, stream>>>(x, xbf, NN * DD / 4);
  xconv_kernel<<<1, 256, 0, stream>>>(u, ubf, NBATCH * DD / 4);
  if (eabf)
    xconv_kernel<<<50000, 256, 0, stream>>>(edge_attr, eabf, NE * DD / 4);

  nhist_kernel<<<(NN + 255) / 256, 256, 0, stream>>>(batch, ncnt);
  ecnt_kernel<<<(NE + 255) / 256, 256, 0, stream>>>(edge_index, batch, ecnt);

  edge_kernel<<<EGRID, 256, 0, stream>>>(
      xbf, eabf, edge_attr, ubf, edge_index, batch,
      wE1t, wE2t, wE3t, eb1, eb2, eb3,
      edge_out, xout_agg, esumPart);

  partred_kernel<<<4, 256, 0, stream>>>(esumPart, esum, EGRID);

  node_kernel<<<NGRID, 256, 0, stream>>>(
      xbf, xout_agg /*agg in*/, xout_agg /*x_out out*/, ubf, batch,
      wN1t, wN2t, wN3t, nb1, nb2, nb3, nsumPart);

  partred_kernel<<<4, 256, 0, stream>>>(nsumPart, nsum, NGRID);

  global_kernel<<<1, 256, 0, stream>>>(
      u, nsum, ncnt, esum, ecnt,
      gW1, gb1, gW2, gb2, gW3, gb3, u_out);
}

// Round 10
// 1040.593 us; speedup vs baseline: 1.0960x; 1.0960x over previous
//
#include <hip/hip_runtime.h>

#define NN 50000
#define NE 400000
#define NBATCH 8
#define DD 128

typedef unsigned short u16;
typedef __attribute__((ext_vector_type(8))) short bf16x8;
typedef __attribute__((ext_vector_type(8))) unsigned short u16x8;
typedef __attribute__((ext_vector_type(4))) unsigned short u16x4;
typedef __attribute__((ext_vector_type(4))) float f32x4;

__device__ __forceinline__ u16 f2bf(float f) {
  union { float f; unsigned u; } a; a.f = f;
  unsigned r = a.u + 0x7fffu + ((a.u >> 16) & 1u);
  return (u16)(r >> 16);
}

__device__ __forceinline__ void glds16(const void* g, void* l) {
  __builtin_amdgcn_global_load_lds(
      (const __attribute__((address_space(1))) unsigned*)g,
      (__attribute__((address_space(3))) unsigned*)l, 16, 0, 0);
}

// Convert+transpose fp32 weight [K][128] -> bf16 chunked [K/128][128 n][128 k]
__global__ void wconv_kernel(const float* __restrict__ src, u16* __restrict__ dst, int K) {
  int idx = blockIdx.x * 256 + threadIdx.x;
  if (idx >= K * 128) return;
  int k = idx >> 7, n = idx & 127;
  dst[((k >> 7) << 14) + (n << 7) + (k & 127)] = f2bf(src[idx]);
}

// fp32 -> bf16 flat copy
__global__ void xconv_kernel(const float* __restrict__ x, u16* __restrict__ xbf, int total4) {
  int i = blockIdx.x * 256 + threadIdx.x;
  if (i >= total4) return;
  f32x4 v = ((const f32x4*)x)[i];
  u16x4 o; o[0]=f2bf(v[0]); o[1]=f2bf(v[1]); o[2]=f2bf(v[2]); o[3]=f2bf(v[3]);
  ((u16x4*)xbf)[i] = o;
}

__global__ void nhist_kernel(const int* __restrict__ batch, unsigned* __restrict__ ncnt) {
  __shared__ unsigned h[NBATCH];
  if (threadIdx.x < NBATCH) h[threadIdx.x] = 0;
  __syncthreads();
  int i = blockIdx.x * 256 + threadIdx.x;
  if (i < NN) atomicAdd(&h[batch[i]], 1u);
  __syncthreads();
  if (threadIdx.x < NBATCH) atomicAdd(&ncnt[threadIdx.x], h[threadIdx.x]);
}

__global__ void ecnt_kernel(const int* __restrict__ edge_index, const int* __restrict__ batch,
                            unsigned* __restrict__ ecnt) {
  __shared__ unsigned h[NBATCH];
  if (threadIdx.x < NBATCH) h[threadIdx.x] = 0;
  __syncthreads();
  int e = blockIdx.x * 256 + threadIdx.x;
  if (e < NE) atomicAdd(&h[batch[edge_index[e]]], 1u);
  __syncthreads();
  if (threadIdx.x < NBATCH) atomicAdd(&ecnt[threadIdx.x], h[threadIdx.x]);
}

// sum per-slot partials [nslot][1024] -> out[1024]
__global__ void partred_kernel(const float* __restrict__ part, float* __restrict__ out, int nslot) {
  int i = blockIdx.x * 256 + threadIdx.x;
  if (i >= NBATCH * 128) return;
  float s = 0.f;
  for (int b = 0; b < nslot; ++b) s += part[(size_t)b * 1024 + i];
  out[i] = s;
}

// ---------------- Edge MLP: 64-edge tile, 32KB LDS dbuf, 4 blocks/CU (R7 frozen) ----------------
// ONLY change vs R7: esum flush -> strided per-slot partials (no contended global atomics)
__global__ __launch_bounds__(256, 4) void edge_kernel(
    const u16* __restrict__ xbf, const u16* __restrict__ eabf /*may be null*/,
    const float* __restrict__ ea_f32, const u16* __restrict__ ubf,
    const int* __restrict__ edge_index, const int* __restrict__ batch,
    const u16* __restrict__ w1, const u16* __restrict__ w2, const u16* __restrict__ w3,
    const float* __restrict__ b1, const float* __restrict__ b2, const float* __restrict__ b3,
    float* __restrict__ edge_out, float* agg,
    float* __restrict__ esumPart)
{
  __shared__ u16 As[2][64 * 128];       // 32 KB double buffer
  __shared__ float red[NBATCH][128];
  __shared__ int rows_s[64], cols_s[64], ebat_s[64];

  const int tid  = threadIdx.x;
  const int lane = tid & 63;
  const int wave = tid >> 6;
  const int wc   = wave;                // 4 waves tile N=128 as 4 x 32 cols
  const int lr   = lane & 15;
  const int lkb  = lane >> 4;
  const int e0   = blockIdx.x * 64;

  if (tid < 64) {
    int r = edge_index[e0 + tid];
    int c = edge_index[NE + e0 + tid];
    rows_s[tid] = r; cols_s[tid] = c;
    ebat_s[tid] = batch[r];
  }
  for (int i = tid; i < NBATCH * 128; i += 256) (&red[0][0])[i] = 0.f;

  f32x4 acc[4][2];
#pragma unroll
  for (int m = 0; m < 4; ++m)
#pragma unroll
    for (int n = 0; n < 2; ++n) { acc[m][n][0]=0.f; acc[m][n][1]=0.f; acc[m][n][2]=0.f; acc[m][n][3]=0.f; }

  __syncthreads();  // indices visible

  auto stage = [&](int buf, int c) {
    if (c == 2 && eabf == nullptr) {
      // fp32 fallback for edge_attr: reg-stage + cvt + swizzled ds_write
#pragma unroll
      for (int j = 0; j < 4; ++j) {
        int idx = j * 64 + lane;
        int rr = wave * 16 + (idx >> 4);
        int k  = idx & 15;
        const float* p = ea_f32 + (size_t)(e0 + rr) * DD + k * 8;
        f32x4 a = *(const f32x4*)p;
        f32x4 b = *(const f32x4*)(p + 4);
        u16x8 v;
        v[0]=f2bf(a[0]); v[1]=f2bf(a[1]); v[2]=f2bf(a[2]); v[3]=f2bf(a[3]);
        v[4]=f2bf(b[0]); v[5]=f2bf(b[1]); v[6]=f2bf(b[2]); v[7]=f2bf(b[3]);
        *(u16x8*)&As[buf][rr * 128 + ((k ^ (rr & 7)) << 3)] = v;
      }
      return;
    }
#pragma unroll
    for (int i = 0; i < 4; ++i) {
      int rr = wave * 16 + i * 4 + (lane >> 4);
      const u16* rp;
      if (c == 0)      rp = xbf + (size_t)rows_s[rr] * DD;
      else if (c == 1) rp = xbf + (size_t)cols_s[rr] * DD;
      else if (c == 2) rp = eabf + (size_t)(e0 + rr) * DD;
      else             rp = ubf + (size_t)ebat_s[rr] * DD;
      const u16* src = rp + (((lane & 15) ^ (rr & 7)) << 3);  // inverse-swizzled source
      u16* dst = &As[buf][(wave * 16 + i * 4) * 128];         // linear wave-uniform dest
      glds16(src, dst);
    }
  };

  auto compute = [&](const u16* AsBuf, const u16* wsrc) {
#pragma unroll
    for (int kk = 0; kk < 4; ++kk) {
      const int k0 = kk * 32 + lkb * 8;
      bf16x8 af[4], bfv[2];
#pragma unroll
      for (int m = 0; m < 4; ++m) {
        int g = m * 16 + lr;
        int slot = kk * 4 + lkb;
        af[m] = *(const bf16x8*)(AsBuf + g * 128 + ((slot ^ (g & 7)) << 3));
      }
#pragma unroll
      for (int n = 0; n < 2; ++n)
        bfv[n] = *(const bf16x8*)(wsrc + ((wc * 32 + n * 16 + lr) << 7) + k0);
#pragma unroll
      for (int m = 0; m < 4; ++m)
#pragma unroll
        for (int n = 0; n < 2; ++n)
          acc[m][n] = __builtin_amdgcn_mfma_f32_16x16x32_bf16(af[m], bfv[n], acc[m][n], 0, 0, 0);
    }
  };

  auto epi_relu = [&](u16* HsBuf, const float* bias) {
#pragma unroll
    for (int n = 0; n < 2; ++n) {
      int colg = wc * 32 + n * 16 + lr;
      float bv = bias[colg];
      int slot = colg >> 3;
#pragma unroll
      for (int m = 0; m < 4; ++m)
#pragma unroll
        for (int r = 0; r < 4; ++r) {
          int rowg = m * 16 + lkb * 4 + r;
          float v = fmaxf(acc[m][n][r] + bv, 0.f);
          HsBuf[rowg * 128 + ((slot ^ (rowg & 7)) << 3) + (colg & 7)] = f2bf(v);
          acc[m][n][r] = 0.f;
        }
    }
  };

  // ---- layer 1: 4 chunks, 2-phase (stage next, compute current, barrier)
  stage(0, 0);
  __syncthreads();
  stage(1, 1); compute(As[0], w1);                __syncthreads();
  stage(0, 2); compute(As[1], w1 + (1 << 14));    __syncthreads();
  stage(1, 3); compute(As[0], w1 + (2 << 14));    __syncthreads();
               compute(As[1], w1 + (3 << 14));
  epi_relu(As[0], b1);
  __syncthreads();
  compute(As[0], w2);
  __syncthreads();
  epi_relu(As[1], b2);
  __syncthreads();
  compute(As[1], w3);

  // epilogue 3: edge_out + agg scatter atomics + per-graph red (LDS)
#pragma unroll
  for (int n = 0; n < 2; ++n) {
    int colg = wc * 32 + n * 16 + lr;
    float bias = b3[colg];
#pragma unroll
    for (int m = 0; m < 4; ++m)
#pragma unroll
      for (int r = 0; r < 4; ++r) {
        int rowg = m * 16 + lkb * 4 + r;
        float v = acc[m][n][r] + bias;
        edge_out[(size_t)(e0 + rowg) * DD + colg] = v;
        atomicAdd(&agg[(size_t)cols_s[rowg] * DD + colg], v);
        atomicAdd(&red[ebat_s[rowg]][colg], v);
      }
  }
  __syncthreads();
  // flush to strided partial slot (bid & 1023): ~6 lightly-contended adds per address
  {
    const int slot = blockIdx.x & 1023;
    for (int i = tid; i < NBATCH * 128; i += 256)
      atomicAdd(&esumPart[((size_t)slot << 10) + i], (&red[0][0])[i]);
  }
}

// ---------------- Node MLP: 64-node tile, 32KB LDS dbuf, 4 blocks/CU (R7 frozen) ----------------
// ONLY change vs R7: nsum flush -> plain per-block partial stores
__global__ __launch_bounds__(256, 4) void node_kernel(
    const u16* __restrict__ xbf, float* aggx /* agg in, x_out out */,
    const u16* __restrict__ ubf, const int* __restrict__ batch,
    const u16* __restrict__ w1, const u16* __restrict__ w2, const u16* __restrict__ w3,
    const float* __restrict__ b1, const float* __restrict__ b2, const float* __restrict__ b3,
    float* __restrict__ nsumPart)
{
  __shared__ u16 As[2][64 * 128];
  __shared__ float red[NBATCH][128];
  __shared__ int nbat_s[64];

  const int tid  = threadIdx.x;
  const int lane = tid & 63;
  const int wave = tid >> 6;
  const int wc   = wave;
  const int lr   = lane & 15;
  const int lkb  = lane >> 4;
  const int n0   = blockIdx.x * 64;

  if (tid < 64) {
    int node = n0 + tid;
    nbat_s[tid] = (node < NN) ? batch[node] : 0;
  }
  for (int i = tid; i < NBATCH * 128; i += 256) (&red[0][0])[i] = 0.f;

  f32x4 acc[4][2];
#pragma unroll
  for (int m = 0; m < 4; ++m)
#pragma unroll
    for (int n = 0; n < 2; ++n) { acc[m][n][0]=0.f; acc[m][n][1]=0.f; acc[m][n][2]=0.f; acc[m][n][3]=0.f; }

  __syncthreads();

  auto stage_bf = [&](int buf, int c) {   // c==0: xbf rows ; c==2: ubf rows
#pragma unroll
    for (int i = 0; i < 4; ++i) {
      int rr = wave * 16 + i * 4 + (lane >> 4);
      int node = n0 + rr; if (node >= NN) node = 0;
      const u16* rp = (c == 0) ? (xbf + (size_t)node * DD)
                               : (ubf + (size_t)nbat_s[rr] * DD);
      const u16* src = rp + (((lane & 15) ^ (rr & 7)) << 3);
      u16* dst = &As[buf][(wave * 16 + i * 4) * 128];
      glds16(src, dst);
    }
  };

  auto stage_agg = [&](int buf) {
#pragma unroll
    for (int j = 0; j < 4; ++j) {
      int idx = j * 64 + lane;
      int rr = wave * 16 + (idx >> 4);
      int k  = idx & 15;
      int node = n0 + rr; if (node >= NN) node = 0;
      const float* p = aggx + (size_t)node * DD + k * 8;
      f32x4 a = *(const f32x4*)p;
      f32x4 b = *(const f32x4*)(p + 4);
      u16x8 v;
      v[0]=f2bf(a[0]); v[1]=f2bf(a[1]); v[2]=f2bf(a[2]); v[3]=f2bf(a[3]);
      v[4]=f2bf(b[0]); v[5]=f2bf(b[1]); v[6]=f2bf(b[2]); v[7]=f2bf(b[3]);
      *(u16x8*)&As[buf][rr * 128 + ((k ^ (rr & 7)) << 3)] = v;
    }
  };

  auto compute = [&](const u16* AsBuf, const u16* wsrc) {
#pragma unroll
    for (int kk = 0; kk < 4; ++kk) {
      const int k0 = kk * 32 + lkb * 8;
      bf16x8 af[4], bfv[2];
#pragma unroll
      for (int m = 0; m < 4; ++m) {
        int g = m * 16 + lr;
        int slot = kk * 4 + lkb;
        af[m] = *(const bf16x8*)(AsBuf + g * 128 + ((slot ^ (g & 7)) << 3));
      }
#pragma unroll
      for (int n = 0; n < 2; ++n)
        bfv[n] = *(const bf16x8*)(wsrc + ((wc * 32 + n * 16 + lr) << 7) + k0);
#pragma unroll
      for (int m = 0; m < 4; ++m)
#pragma unroll
        for (int n = 0; n < 2; ++n)
          acc[m][n] = __builtin_amdgcn_mfma_f32_16x16x32_bf16(af[m], bfv[n], acc[m][n], 0, 0, 0);
    }
  };

  auto epi_relu = [&](u16* HsBuf, const float* bias) {
#pragma unroll
    for (int n = 0; n < 2; ++n) {
      int colg = wc * 32 + n * 16 + lr;
      float bv = bias[colg];
      int slot = colg >> 3;
#pragma unroll
      for (int m = 0; m < 4; ++m)
#pragma unroll
        for (int r = 0; r < 4; ++r) {
          int rowg = m * 16 + lkb * 4 + r;
          float v = fmaxf(acc[m][n][r] + bv, 0.f);
          HsBuf[rowg * 128 + ((slot ^ (rowg & 7)) << 3) + (colg & 7)] = f2bf(v);
          acc[m][n][r] = 0.f;
        }
    }
  };

  // layer 1: 3 chunks (x | agg | u), 2-phase
  stage_bf(0, 0);
  __syncthreads();
  stage_agg(1);   compute(As[0], w1);               __syncthreads();
  stage_bf(0, 2); compute(As[1], w1 + (1 << 14));   __syncthreads();
                  compute(As[0], w1 + (2 << 14));
  epi_relu(As[1], b1);
  __syncthreads();
  compute(As[1], w2);
  __syncthreads();
  epi_relu(As[0], b2);
  __syncthreads();
  compute(As[0], w3);

  // epilogue 3: x_out overwrites agg rows; node-mean partials
#pragma unroll
  for (int n = 0; n < 2; ++n) {
    int colg = wc * 32 + n * 16 + lr;
    float bias = b3[colg];
#pragma unroll
    for (int m = 0; m < 4; ++m)
#pragma unroll
      for (int r = 0; r < 4; ++r) {
        int rowg = m * 16 + lkb * 4 + r;
        int node = n0 + rowg;
        if (node < NN) {
          float v = acc[m][n][r] + bias;
          aggx[(size_t)node * DD + colg] = v;
          atomicAdd(&red[nbat_s[rowg]][colg], v);
        }
      }
  }
  __syncthreads();
  for (int i = tid; i < NBATCH * 128; i += 256)
    nsumPart[((size_t)blockIdx.x << 10) + i] = (&red[0][0])[i];
}

// ---------------- Global MLP (fp32, tiny) ----------------
__global__ void global_kernel(
    const float* __restrict__ u,
    const float* __restrict__ nsum, const unsigned* __restrict__ ncnt,
    const float* __restrict__ esum, const unsigned* __restrict__ ecnt,
    const float* __restrict__ gW1, const float* __restrict__ gb1,
    const float* __restrict__ gW2, const float* __restrict__ gb2,
    const float* __restrict__ gW3, const float* __restrict__ gb3,
    float* __restrict__ u_out)
{
  __shared__ float gin[NBATCH][384];
  __shared__ float h1[NBATCH][128];
  __shared__ float h2[NBATCH][128];
  int tid = threadIdx.x;
  for (int i = tid; i < NBATCH * 128; i += 256) {
    int r = i >> 7, c = i & 127;
    float nc = (float)(ncnt[r] < 1u ? 1u : ncnt[r]);
    float ec = (float)(ecnt[r] < 1u ? 1u : ecnt[r]);
    gin[r][c] = u[i];
    gin[r][128 + c] = nsum[i] / nc;
    gin[r][256 + c] = esum[i] / ec;
  }
  __syncthreads();
  for (int o = tid; o < NBATCH * 128; o += 256) {
    int r = o >> 7, n = o & 127;
    float s = gb1[n];
    for (int k = 0; k < 384; ++k) s += gin[r][k] * gW1[k * 128 + n];
    h1[r][n] = fmaxf(s, 0.f);
  }
  __syncthreads();
  for (int o = tid; o < NBATCH * 128; o += 256) {
    int r = o >> 7, n = o & 127;
    float s = gb2[n];
    for (int k = 0; k < 128; ++k) s += h1[r][k] * gW2[k * 128 + n];
    h2[r][n] = fmaxf(s, 0.f);
  }
  __syncthreads();
  for (int o = tid; o < NBATCH * 128; o += 256) {
    int r = o >> 7, n = o & 127;
    float s = gb3[n];
    for (int k = 0; k < 128; ++k) s += h2[r][k] * gW3[k * 128 + n];
    u_out[o] = s;
  }
}

extern "C" void kernel_launch(void* const* d_in, const int* in_sizes, int n_in,
                              void* d_out, int out_size, void* d_ws, size_t ws_size,
                              hipStream_t stream) {
  const float* x          = (const float*)d_in[0];
  const int*   edge_index = (const int*)d_in[1];
  const float* edge_attr  = (const float*)d_in[2];
  const float* u          = (const float*)d_in[3];
  const int*   batch      = (const int*)d_in[4];
  const float* eW1 = (const float*)d_in[5];  const float* eb1 = (const float*)d_in[6];
  const float* eW2 = (const float*)d_in[7];  const float* eb2 = (const float*)d_in[8];
  const float* eW3 = (const float*)d_in[9];  const float* eb3 = (const float*)d_in[10];
  const float* nW1 = (const float*)d_in[11]; const float* nb1 = (const float*)d_in[12];
  const float* nW2 = (const float*)d_in[13]; const float* nb2 = (const float*)d_in[14];
  const float* nW3 = (const float*)d_in[15]; const float* nb3 = (const float*)d_in[16];
  const float* gW1 = (const float*)d_in[17]; const float* gb1 = (const float*)d_in[18];
  const float* gW2 = (const float*)d_in[19]; const float* gb2 = (const float*)d_in[20];
  const float* gW3 = (const float*)d_in[21]; const float* gb3 = (const float*)d_in[22];

  float* out      = (float*)d_out;
  float* xout_agg = out;                                  // [NN][128]: agg then x_out
  float* edge_out = out + (size_t)NN * DD;                // [NE][128]
  float* u_out    = out + (size_t)(NN + NE) * DD;         // [8][128]

  char* ws = (char*)d_ws;
  u16* wE1t = (u16*)(ws + 0);         // 131072
  u16* wE2t = (u16*)(ws + 131072);    // 32768
  u16* wE3t = (u16*)(ws + 163840);    // 32768
  u16* wN1t = (u16*)(ws + 196608);    // 98304
  u16* wN2t = (u16*)(ws + 294912);    // 32768
  u16* wN3t = (u16*)(ws + 327680);    // 32768
  float*    esum = (float*)(ws + 360448);     // 4096
  float*    nsum = (float*)(ws + 364544);     // 4096
  unsigned* ecnt = (unsigned*)(ws + 368640);  // 32
  unsigned* ncnt = (unsigned*)(ws + 368672);  // 32
  u16*      ubf  = (u16*)(ws + 369664);       // 2048
  u16*      xbf  = (u16*)(ws + 393216);       // 12,800,000 -> ends 13,193,216
  const size_t EABF_OFF = 13193216;
  const size_t EABF_END = EABF_OFF + (size_t)NE * DD * 2;      // 115,593,216
  const size_t ESUMP_OFF = 115593216;                          // 1024*1024*4 = 4,194,304
  const size_t NSUMP_OFF = 119787520;                          // 782*1024*4 = 3,203,072 -> ends 122,990,592
  const size_t WS_NEED   = 122990592;
  u16*   eabf     = (ws_size >= WS_NEED) ? (u16*)(ws + EABF_OFF) : nullptr;
  float* esumPart = (float*)(ws + ESUMP_OFF);
  float* nsumPart = (float*)(ws + NSUMP_OFF);
  const int NODE_BLOCKS = (NN + 63) / 64;   // 782

  // zero agg region (x_out part of d_out), count accumulators, esum partials
  hipMemsetAsync(d_out, 0, (size_t)NN * DD * sizeof(float), stream);
  hipMemsetAsync(ws + 368640, 0, 64, stream);
  if (eabf) hipMemsetAsync(ws + ESUMP_OFF, 0, 4194304, stream);
  else      hipMemsetAsync(ws + 360448, 0, 8192, stream);

  wconv_kernel<<<256, 256, 0, stream>>>(eW1, wE1t, 512);
  wconv_kernel<<<64, 256, 0, stream>>>(eW2, wE2t, 128);
  wconv_kernel<<<64, 256, 0, stream>>>(eW3, wE3t, 128);
  wconv_kernel<<<192, 256, 0, stream>>>(nW1, wN1t, 384);
  wconv_kernel<<<64, 256, 0, stream>>>(nW2, wN2t, 128);
  wconv_kernel<<<64, 256, 0, stream>>>(nW3, wN3t, 128);
  xconv_kernel<<<6250, 256, 0, stream>>>(x, xbf, NN * DD / 4);
  xconv_kernel<<<1, 256, 0, stream>>>(u, ubf, NBATCH * DD / 4);
  if (eabf)
    xconv_kernel<<<50000, 256, 0, stream>>>(edge_attr, eabf, NE * DD / 4);

  nhist_kernel<<<(NN + 255) / 256, 256, 0, stream>>>(batch, ncnt);
  ecnt_kernel<<<(NE + 255) / 256, 256, 0, stream>>>(edge_index, batch, ecnt);

  edge_kernel<<<NE / 64, 256, 0, stream>>>(
      xbf, eabf, edge_attr, ubf, edge_index, batch,
      wE1t, wE2t, wE3t, eb1, eb2, eb3,
      edge_out, xout_agg, esumPart);

  partred_kernel<<<4, 256, 0, stream>>>(esumPart, esum, 1024);

  node_kernel<<<NODE_BLOCKS, 256, 0, stream>>>(
      xbf, xout_agg, ubf, batch,
      wN1t, wN2t, wN3t, nb1, nb2, nb3,
      nsumPart);

  partred_kernel<<<4, 256, 0, stream>>>(nsumPart, nsum, NODE_BLOCKS);

  global_kernel<<<1, 256, 0, stream>>>(
      u, nsum, ncnt, esum, ecnt,
      gW1, gb1, gW2, gb2, gW3, gb3, u_out);
}

// Round 11
// 686.022 us; speedup vs baseline: 1.6624x; 1.5169x over previous
//
#include <hip/hip_runtime.h>

#define NN 50000
#define NE 400000
#define NBATCH 8
#define DD 128
#define SCAN_BLK 1024

typedef unsigned short u16;
typedef __attribute__((ext_vector_type(8))) short bf16x8;
typedef __attribute__((ext_vector_type(8))) unsigned short u16x8;
typedef __attribute__((ext_vector_type(4))) unsigned short u16x4;
typedef __attribute__((ext_vector_type(4))) float f32x4;
typedef __attribute__((ext_vector_type(2))) float f32x2;

__device__ __forceinline__ u16 f2bf(float f) {
  union { float f; unsigned u; } a; a.f = f;
  unsigned r = a.u + 0x7fffu + ((a.u >> 16) & 1u);
  return (u16)(r >> 16);
}

__device__ __forceinline__ void glds16(const void* g, void* l) {
  __builtin_amdgcn_global_load_lds(
      (const __attribute__((address_space(1))) unsigned*)g,
      (__attribute__((address_space(3))) unsigned*)l, 16, 0, 0);
}

// Convert+transpose fp32 weight [K][128] -> bf16 chunked [K/128][128 n][128 k]
__global__ void wconv_kernel(const float* __restrict__ src, u16* __restrict__ dst, int K) {
  int idx = blockIdx.x * 256 + threadIdx.x;
  if (idx >= K * 128) return;
  int k = idx >> 7, n = idx & 127;
  dst[((k >> 7) << 14) + (n << 7) + (k & 127)] = f2bf(src[idx]);
}

// fp32 -> bf16 flat copy
__global__ void xconv_kernel(const float* __restrict__ x, u16* __restrict__ xbf, int total4) {
  int i = blockIdx.x * 256 + threadIdx.x;
  if (i >= total4) return;
  f32x4 v = ((const f32x4*)x)[i];
  u16x4 o; o[0]=f2bf(v[0]); o[1]=f2bf(v[1]); o[2]=f2bf(v[2]); o[3]=f2bf(v[3]);
  ((u16x4*)xbf)[i] = o;
}

__global__ void nhist_kernel(const int* __restrict__ batch, unsigned* __restrict__ ncnt) {
  __shared__ unsigned h[NBATCH];
  if (threadIdx.x < NBATCH) h[threadIdx.x] = 0;
  __syncthreads();
  int i = blockIdx.x * 256 + threadIdx.x;
  if (i < NN) atomicAdd(&h[batch[i]], 1u);
  __syncthreads();
  if (threadIdx.x < NBATCH) atomicAdd(&ncnt[threadIdx.x], h[threadIdx.x]);
}

// ---------- CSR prep (R2/R8-proven) ----------
__global__ void ehist_kernel(const int* __restrict__ edge_index, const int* __restrict__ batch,
                             int* __restrict__ cnt, unsigned* __restrict__ ecnt) {
  __shared__ unsigned h[NBATCH];
  if (threadIdx.x < NBATCH) h[threadIdx.x] = 0;
  __syncthreads();
  int e = blockIdx.x * 256 + threadIdx.x;
  if (e < NE) {
    int col = edge_index[NE + e];
    atomicAdd(&cnt[col], 1);
    int row = edge_index[e];
    atomicAdd(&h[batch[row]], 1u);
  }
  __syncthreads();
  if (threadIdx.x < NBATCH) atomicAdd(&ecnt[threadIdx.x], h[threadIdx.x]);
}

__global__ void scan1_kernel(const int* __restrict__ cnt, int* __restrict__ offs,
                             int* __restrict__ bsum, int n) {
  __shared__ int lds[256];
  int b0 = blockIdx.x * SCAN_BLK;
  int t = threadIdx.x;
  int i0 = b0 + t * 4;
  int v[4]; int s = 0;
#pragma unroll
  for (int k = 0; k < 4; ++k) { int idx = i0 + k; int c = (idx < n) ? cnt[idx] : 0; v[k] = s; s += c; }
  lds[t] = s;
  __syncthreads();
  for (int off = 1; off < 256; off <<= 1) {
    int x = (t >= off) ? lds[t - off] : 0;
    __syncthreads();
    lds[t] += x;
    __syncthreads();
  }
  int texcl = (t > 0) ? lds[t - 1] : 0;
#pragma unroll
  for (int k = 0; k < 4; ++k) { int idx = i0 + k; if (idx < n) offs[idx] = texcl + v[k]; }
  if (t == 255) bsum[blockIdx.x] = lds[255];
}

__global__ void scan2_kernel(int* __restrict__ bsum, int nb) {
  if (threadIdx.x == 0) {
    int s = 0;
    for (int i = 0; i < nb; ++i) { int c = bsum[i]; bsum[i] = s; s += c; }
  }
}

__global__ void scan3_kernel(int* __restrict__ offs, int* __restrict__ cursor,
                             const int* __restrict__ bsum, int n, int total) {
  int i = blockIdx.x * 256 + threadIdx.x;
  if (i < n) {
    int v = offs[i] + bsum[i / SCAN_BLK];
    offs[i] = v;
    cursor[i] = v;
  }
  if (i == 0) offs[n] = total;
}

__global__ void scatter_kernel(const int* __restrict__ edge_index, int* __restrict__ cursor,
                               int* __restrict__ perm) {
  int e = blockIdx.x * 256 + threadIdx.x;
  if (e < NE) {
    int col = edge_index[NE + e];
    int pos = atomicAdd(&cursor[col], 1);
    perm[pos] = e;
  }
}

// ---------- agg gather-sum: ONE WAVE PER NODE, coalesced 512B rows (R8-proven) ----------
__global__ __launch_bounds__(256, 8) void agg_kernel(
    const float* __restrict__ edge_out, const int* __restrict__ offs,
    const int* __restrict__ perm, float* __restrict__ agg) {
  int w = (blockIdx.x * 256 + threadIdx.x) >> 6;   // wave id == node id
  int lane = threadIdx.x & 63;
  if (w >= NN) return;
  int j0 = offs[w], j1 = offs[w + 1];
  const f32x2* base = (const f32x2*)edge_out;
  f32x2 s = {0.f, 0.f};
  int j = j0;
  for (; j + 1 < j1; j += 2) {
    int e0 = perm[j], e1 = perm[j + 1];
    f32x2 v0 = base[(size_t)e0 * 64 + lane];
    f32x2 v1 = base[(size_t)e1 * 64 + lane];
    s += v0; s += v1;
  }
  if (j < j1) {
    int e = perm[j];
    s += base[(size_t)e * 64 + lane];
  }
  ((f32x2*)agg)[(size_t)w * 64 + lane] = s;
}

// ---------- parallel partial reduce: [nslot][1024] -> out[1024] (R10 bug fixed) ----------
#define PR_SPAN 32
__global__ void partred_kernel(const float* __restrict__ part, float* __restrict__ out, int nslot) {
  int b0 = blockIdx.x * PR_SPAN;
  int i = threadIdx.x;
  int bend = b0 + PR_SPAN; if (bend > nslot) bend = nslot;
  float s0 = 0.f, s1 = 0.f, s2 = 0.f, s3 = 0.f;
  for (int b = b0; b < bend; ++b) {
    const float* p = part + (size_t)b * 1024;
    s0 += p[i]; s1 += p[256 + i]; s2 += p[512 + i]; s3 += p[768 + i];
  }
  atomicAdd(&out[i], s0);
  atomicAdd(&out[256 + i], s1);
  atomicAdd(&out[512 + i], s2);
  atomicAdd(&out[768 + i], s3);
}

// ---------------- Edge MLP: 64-edge tile, 32KB dbuf, 4 blk/CU — ZERO global atomics ----------------
__global__ __launch_bounds__(256, 4) void edge_kernel(
    const u16* __restrict__ xbf,
    const float* __restrict__ ea_f32, const u16* __restrict__ ubf,
    const int* __restrict__ edge_index, const int* __restrict__ batch,
    const u16* __restrict__ w1, const u16* __restrict__ w2, const u16* __restrict__ w3,
    const float* __restrict__ b1, const float* __restrict__ b2, const float* __restrict__ b3,
    float* __restrict__ edge_out, float* __restrict__ esumPart)
{
  __shared__ u16 As[2][64 * 128];       // 32 KB double buffer
  __shared__ float red[NBATCH][128];
  __shared__ int rows_s[64], cols_s[64], ebat_s[64];

  const int tid  = threadIdx.x;
  const int lane = tid & 63;
  const int wave = tid >> 6;
  const int wc   = wave;                // 4 waves tile N=128 as 4 x 32 cols
  const int lr   = lane & 15;
  const int lkb  = lane >> 4;
  const int e0   = blockIdx.x * 64;

  if (tid < 64) {
    int r = edge_index[e0 + tid];
    int c = edge_index[NE + e0 + tid];
    rows_s[tid] = r; cols_s[tid] = c;
    ebat_s[tid] = batch[r];
  }
  for (int i = tid; i < NBATCH * 128; i += 256) (&red[0][0])[i] = 0.f;

  f32x4 acc[4][2];
#pragma unroll
  for (int m = 0; m < 4; ++m)
#pragma unroll
    for (int n = 0; n < 2; ++n) { acc[m][n][0]=0.f; acc[m][n][1]=0.f; acc[m][n][2]=0.f; acc[m][n][3]=0.f; }

  __syncthreads();  // indices visible

  auto stage = [&](int buf, int c) {
    if (c == 2) {
      // edge_attr fp32: reg-stage + cvt + swizzled ds_write (coalesced 512B/row)
#pragma unroll
      for (int j = 0; j < 4; ++j) {
        int idx = j * 64 + lane;
        int rr = wave * 16 + (idx >> 4);
        int k  = idx & 15;
        const float* p = ea_f32 + (size_t)(e0 + rr) * DD + k * 8;
        f32x4 a = *(const f32x4*)p;
        f32x4 b = *(const f32x4*)(p + 4);
        u16x8 v;
        v[0]=f2bf(a[0]); v[1]=f2bf(a[1]); v[2]=f2bf(a[2]); v[3]=f2bf(a[3]);
        v[4]=f2bf(b[0]); v[5]=f2bf(b[1]); v[6]=f2bf(b[2]); v[7]=f2bf(b[3]);
        *(u16x8*)&As[buf][rr * 128 + ((k ^ (rr & 7)) << 3)] = v;
      }
      return;
    }
#pragma unroll
    for (int i = 0; i < 4; ++i) {
      int rr = wave * 16 + i * 4 + (lane >> 4);
      const u16* rp;
      if (c == 0)      rp = xbf + (size_t)rows_s[rr] * DD;
      else if (c == 1) rp = xbf + (size_t)cols_s[rr] * DD;
      else             rp = ubf + (size_t)ebat_s[rr] * DD;
      const u16* src = rp + (((lane & 15) ^ (rr & 7)) << 3);  // inverse-swizzled source
      u16* dst = &As[buf][(wave * 16 + i * 4) * 128];         // linear wave-uniform dest
      glds16(src, dst);
    }
  };

  auto compute = [&](const u16* AsBuf, const u16* wsrc) {
#pragma unroll
    for (int kk = 0; kk < 4; ++kk) {
      const int k0 = kk * 32 + lkb * 8;
      bf16x8 af[4], bfv[2];
#pragma unroll
      for (int m = 0; m < 4; ++m) {
        int g = m * 16 + lr;
        int slot = kk * 4 + lkb;
        af[m] = *(const bf16x8*)(AsBuf + g * 128 + ((slot ^ (g & 7)) << 3));
      }
#pragma unroll
      for (int n = 0; n < 2; ++n)
        bfv[n] = *(const bf16x8*)(wsrc + ((wc * 32 + n * 16 + lr) << 7) + k0);
#pragma unroll
      for (int m = 0; m < 4; ++m)
#pragma unroll
        for (int n = 0; n < 2; ++n)
          acc[m][n] = __builtin_amdgcn_mfma_f32_16x16x32_bf16(af[m], bfv[n], acc[m][n], 0, 0, 0);
    }
  };

  auto epi_relu = [&](u16* HsBuf, const float* bias) {
#pragma unroll
    for (int n = 0; n < 2; ++n) {
      int colg = wc * 32 + n * 16 + lr;
      float bv = bias[colg];
      int slot = colg >> 3;
#pragma unroll
      for (int m = 0; m < 4; ++m)
#pragma unroll
        for (int r = 0; r < 4; ++r) {
          int rowg = m * 16 + lkb * 4 + r;
          float v = fmaxf(acc[m][n][r] + bv, 0.f);
          HsBuf[rowg * 128 + ((slot ^ (rowg & 7)) << 3) + (colg & 7)] = f2bf(v);
          acc[m][n][r] = 0.f;
        }
    }
  };

  // ---- layer 1: 4 chunks, 2-phase (stage next, compute current, barrier)
  stage(0, 0);
  __syncthreads();
  stage(1, 1); compute(As[0], w1);                __syncthreads();
  stage(0, 2); compute(As[1], w1 + (1 << 14));    __syncthreads();
  stage(1, 3); compute(As[0], w1 + (2 << 14));    __syncthreads();
               compute(As[1], w1 + (3 << 14));
  epi_relu(As[0], b1);
  __syncthreads();
  compute(As[0], w2);
  __syncthreads();
  epi_relu(As[1], b2);
  __syncthreads();
  compute(As[1], w3);

  // epilogue 3: edge_out stores + per-graph red (LDS atomics only)
#pragma unroll
  for (int n = 0; n < 2; ++n) {
    int colg = wc * 32 + n * 16 + lr;
    float bias = b3[colg];
#pragma unroll
    for (int m = 0; m < 4; ++m)
#pragma unroll
      for (int r = 0; r < 4; ++r) {
        int rowg = m * 16 + lkb * 4 + r;
        float v = acc[m][n][r] + bias;
        edge_out[(size_t)(e0 + rowg) * DD + colg] = v;
        atomicAdd(&red[ebat_s[rowg]][colg], v);
      }
  }
  __syncthreads();
  // plain-store flush of per-block partial (no global atomics)
  for (int i = tid; i < NBATCH * 128; i += 256)
    esumPart[((size_t)blockIdx.x << 10) + i] = (&red[0][0])[i];
}

// ---------------- Node MLP: 64-node tile, CSR agg source (R10 structure) ----------------
__global__ __launch_bounds__(256, 4) void node_kernel(
    const u16* __restrict__ xbf, const float* __restrict__ aggsrc,
    float* __restrict__ x_out,
    const u16* __restrict__ ubf, const int* __restrict__ batch,
    const u16* __restrict__ w1, const u16* __restrict__ w2, const u16* __restrict__ w3,
    const float* __restrict__ b1, const float* __restrict__ b2, const float* __restrict__ b3,
    float* __restrict__ nsumPart)
{
  __shared__ u16 As[2][64 * 128];
  __shared__ float red[NBATCH][128];
  __shared__ int nbat_s[64];

  const int tid  = threadIdx.x;
  const int lane = tid & 63;
  const int wave = tid >> 6;
  const int wc   = wave;
  const int lr   = lane & 15;
  const int lkb  = lane >> 4;
  const int n0   = blockIdx.x * 64;

  if (tid < 64) {
    int node = n0 + tid;
    nbat_s[tid] = (node < NN) ? batch[node] : 0;
  }
  for (int i = tid; i < NBATCH * 128; i += 256) (&red[0][0])[i] = 0.f;

  f32x4 acc[4][2];
#pragma unroll
  for (int m = 0; m < 4; ++m)
#pragma unroll
    for (int n = 0; n < 2; ++n) { acc[m][n][0]=0.f; acc[m][n][1]=0.f; acc[m][n][2]=0.f; acc[m][n][3]=0.f; }

  __syncthreads();

  auto stage_bf = [&](int buf, int c) {   // c==0: xbf rows ; c==2: ubf rows
#pragma unroll
    for (int i = 0; i < 4; ++i) {
      int rr = wave * 16 + i * 4 + (lane >> 4);
      int node = n0 + rr; if (node >= NN) node = 0;
      const u16* rp = (c == 0) ? (xbf + (size_t)node * DD)
                               : (ubf + (size_t)nbat_s[rr] * DD);
      const u16* src = rp + (((lane & 15) ^ (rr & 7)) << 3);
      u16* dst = &As[buf][(wave * 16 + i * 4) * 128];
      glds16(src, dst);
    }
  };

  auto stage_agg = [&](int buf) {
#pragma unroll
    for (int j = 0; j < 4; ++j) {
      int idx = j * 64 + lane;
      int rr = wave * 16 + (idx >> 4);
      int k  = idx & 15;
      int node = n0 + rr; if (node >= NN) node = 0;
      const float* p = aggsrc + (size_t)node * DD + k * 8;
      f32x4 a = *(const f32x4*)p;
      f32x4 b = *(const f32x4*)(p + 4);
      u16x8 v;
      v[0]=f2bf(a[0]); v[1]=f2bf(a[1]); v[2]=f2bf(a[2]); v[3]=f2bf(a[3]);
      v[4]=f2bf(b[0]); v[5]=f2bf(b[1]); v[6]=f2bf(b[2]); v[7]=f2bf(b[3]);
      *(u16x8*)&As[buf][rr * 128 + ((k ^ (rr & 7)) << 3)] = v;
    }
  };

  auto compute = [&](const u16* AsBuf, const u16* wsrc) {
#pragma unroll
    for (int kk = 0; kk < 4; ++kk) {
      const int k0 = kk * 32 + lkb * 8;
      bf16x8 af[4], bfv[2];
#pragma unroll
      for (int m = 0; m < 4; ++m) {
        int g = m * 16 + lr;
        int slot = kk * 4 + lkb;
        af[m] = *(const bf16x8*)(AsBuf + g * 128 + ((slot ^ (g & 7)) << 3));
      }
#pragma unroll
      for (int n = 0; n < 2; ++n)
        bfv[n] = *(const bf16x8*)(wsrc + ((wc * 32 + n * 16 + lr) << 7) + k0);
#pragma unroll
      for (int m = 0; m < 4; ++m)
#pragma unroll
        for (int n = 0; n < 2; ++n)
          acc[m][n] = __builtin_amdgcn_mfma_f32_16x16x32_bf16(af[m], bfv[n], acc[m][n], 0, 0, 0);
    }
  };

  auto epi_relu = [&](u16* HsBuf, const float* bias) {
#pragma unroll
    for (int n = 0; n < 2; ++n) {
      int colg = wc * 32 + n * 16 + lr;
      float bv = bias[colg];
      int slot = colg >> 3;
#pragma unroll
      for (int m = 0; m < 4; ++m)
#pragma unroll
        for (int r = 0; r < 4; ++r) {
          int rowg = m * 16 + lkb * 4 + r;
          float v = fmaxf(acc[m][n][r] + bv, 0.f);
          HsBuf[rowg * 128 + ((slot ^ (rowg & 7)) << 3) + (colg & 7)] = f2bf(v);
          acc[m][n][r] = 0.f;
        }
    }
  };

  // layer 1: 3 chunks (x | agg | u), 2-phase
  stage_bf(0, 0);
  __syncthreads();
  stage_agg(1);   compute(As[0], w1);               __syncthreads();
  stage_bf(0, 2); compute(As[1], w1 + (1 << 14));   __syncthreads();
                  compute(As[0], w1 + (2 << 14));
  epi_relu(As[1], b1);
  __syncthreads();
  compute(As[1], w2);
  __syncthreads();
  epi_relu(As[0], b2);
  __syncthreads();
  compute(As[0], w3);

  // epilogue 3: x_out stores; node-mean partials (LDS atomics only)
#pragma unroll
  for (int n = 0; n < 2; ++n) {
    int colg = wc * 32 + n * 16 + lr;
    float bias = b3[colg];
#pragma unroll
    for (int m = 0; m < 4; ++m)
#pragma unroll
      for (int r = 0; r < 4; ++r) {
        int rowg = m * 16 + lkb * 4 + r;
        int node = n0 + rowg;
        if (node < NN) {
          float v = acc[m][n][r] + bias;
          x_out[(size_t)node * DD + colg] = v;
          atomicAdd(&red[nbat_s[rowg]][colg], v);
        }
      }
  }
  __syncthreads();
  for (int i = tid; i < NBATCH * 128; i += 256)
    nsumPart[((size_t)blockIdx.x << 10) + i] = (&red[0][0])[i];
}

// ---------------- Global MLP (fp32, tiny) ----------------
__global__ void global_kernel(
    const float* __restrict__ u,
    const float* __restrict__ nsum, const unsigned* __restrict__ ncnt,
    const float* __restrict__ esum, const unsigned* __restrict__ ecnt,
    const float* __restrict__ gW1, const float* __restrict__ gb1,
    const float* __restrict__ gW2, const float* __restrict__ gb2,
    const float* __restrict__ gW3, const float* __restrict__ gb3,
    float* __restrict__ u_out)
{
  __shared__ float gin[NBATCH][384];
  __shared__ float h1[NBATCH][128];
  __shared__ float h2[NBATCH][128];
  int tid = threadIdx.x;
  for (int i = tid; i < NBATCH * 128; i += 256) {
    int r = i >> 7, c = i & 127;
    float nc = (float)(ncnt[r] < 1u ? 1u : ncnt[r]);
    float ec = (float)(ecnt[r] < 1u ? 1u : ecnt[r]);
    gin[r][c] = u[i];
    gin[r][128 + c] = nsum[i] / nc;
    gin[r][256 + c] = esum[i] / ec;
  }
  __syncthreads();
  for (int o = tid; o < NBATCH * 128; o += 256) {
    int r = o >> 7, n = o & 127;
    float s = gb1[n];
    for (int k = 0; k < 384; ++k) s += gin[r][k] * gW1[k * 128 + n];
    h1[r][n] = fmaxf(s, 0.f);
  }
  __syncthreads();
  for (int o = tid; o < NBATCH * 128; o += 256) {
    int r = o >> 7, n = o & 127;
    float s = gb2[n];
    for (int k = 0; k < 128; ++k) s += h1[r][k] * gW2[k * 128 + n];
    h2[r][n] = fmaxf(s, 0.f);
  }
  __syncthreads();
  for (int o = tid; o < NBATCH * 128; o += 256) {
    int r = o >> 7, n = o & 127;
    float s = gb3[n];
    for (int k = 0; k < 128; ++k) s += h2[r][k] * gW3[k * 128 + n];
    u_out[o] = s;
  }
}

extern "C" void kernel_launch(void* const* d_in, const int* in_sizes, int n_in,
                              void* d_out, int out_size, void* d_ws, size_t ws_size,
                              hipStream_t stream) {
  const float* x          = (const float*)d_in[0];
  const int*   edge_index = (const int*)d_in[1];
  const float* edge_attr  = (const float*)d_in[2];
  const float* u          = (const float*)d_in[3];
  const int*   batch      = (const int*)d_in[4];
  const float* eW1 = (const float*)d_in[5];  const float* eb1 = (const float*)d_in[6];
  const float* eW2 = (const float*)d_in[7];  const float* eb2 = (const float*)d_in[8];
  const float* eW3 = (const float*)d_in[9];  const float* eb3 = (const float*)d_in[10];
  const float* nW1 = (const float*)d_in[11]; const float* nb1 = (const float*)d_in[12];
  const float* nW2 = (const float*)d_in[13]; const float* nb2 = (const float*)d_in[14];
  const float* nW3 = (const float*)d_in[15]; const float* nb3 = (const float*)d_in[16];
  const float* gW1 = (const float*)d_in[17]; const float* gb1 = (const float*)d_in[18];
  const float* gW2 = (const float*)d_in[19]; const float* gb2 = (const float*)d_in[20];
  const float* gW3 = (const float*)d_in[21]; const float* gb3 = (const float*)d_in[22];

  float* out      = (float*)d_out;
  float* x_out    = out;                                  // [NN][128]
  float* edge_out = out + (size_t)NN * DD;                // [NE][128]
  float* u_out    = out + (size_t)(NN + NE) * DD;         // [8][128]

  char* ws = (char*)d_ws;
  u16* wE1t = (u16*)(ws + 0);         // 131072
  u16* wE2t = (u16*)(ws + 131072);    // 32768
  u16* wE3t = (u16*)(ws + 163840);    // 32768
  u16* wN1t = (u16*)(ws + 196608);    // 98304
  u16* wN2t = (u16*)(ws + 294912);    // 32768
  u16* wN3t = (u16*)(ws + 327680);    // 32768
  float*    esum = (float*)(ws + 360448);     // 4096
  float*    nsum = (float*)(ws + 364544);     // 4096
  unsigned* ecnt = (unsigned*)(ws + 368640);  // 32
  unsigned* ncnt = (unsigned*)(ws + 368672);  // 32
  u16*      ubf  = (u16*)(ws + 369664);       // 2048
  u16*      xbf  = (u16*)(ws + 393216);       // 12,800,000 -> ends 13,193,216
  float* esumPart = (float*)(ws + 13193216);  // 6250*4096 = 25,600,000 -> 38,793,216
  float* nsumPart = (float*)(ws + 38793216);  // 782*4096  =  3,203,072 -> 41,996,288
  int*   cnt      = (int*)(ws + 41996288);    // 200,000 -> 42,196,288
  int*   offs     = (int*)(ws + 42196288);    // 200,004 -> pad to 42,396,352
  int*   cursor   = (int*)(ws + 42396352);    // 200,000 -> 42,596,352
  int*   bsum     = (int*)(ws + 42596352);    // pad to 42,596,608
  int*   perm     = (int*)(ws + 42596608);    // 1,600,000 -> 44,196,608
  float* agg      = (float*)(ws + 44196608);  // 25,600,000 -> ends 69,796,608

  const int NODE_BLOCKS = (NN + 63) / 64;     // 782
  const int EDGE_BLOCKS = NE / 64;            // 6250

  // zero: esum/nsum/ecnt/ncnt (8288 B) + cnt histogram (200 KB)
  hipMemsetAsync(ws + 360448, 0, 8288, stream);
  hipMemsetAsync(ws + 41996288, 0, 200000, stream);

  wconv_kernel<<<256, 256, 0, stream>>>(eW1, wE1t, 512);
  wconv_kernel<<<64, 256, 0, stream>>>(eW2, wE2t, 128);
  wconv_kernel<<<64, 256, 0, stream>>>(eW3, wE3t, 128);
  wconv_kernel<<<192, 256, 0, stream>>>(nW1, wN1t, 384);
  wconv_kernel<<<64, 256, 0, stream>>>(nW2, wN2t, 128);
  wconv_kernel<<<64, 256, 0, stream>>>(nW3, wN3t, 128);
  xconv_kernel<<<6250, 256, 0, stream>>>(x, xbf, NN * DD / 4);
  xconv_kernel<<<1, 256, 0, stream>>>(u, ubf, NBATCH * DD / 4);

  nhist_kernel<<<(NN + 255) / 256, 256, 0, stream>>>(batch, ncnt);

  // CSR prep (ehist also produces ecnt)
  ehist_kernel<<<(NE + 255) / 256, 256, 0, stream>>>(edge_index, batch, cnt, ecnt);
  scan1_kernel<<<(NN + SCAN_BLK - 1) / SCAN_BLK, 256, 0, stream>>>(cnt, offs, bsum, NN);
  scan2_kernel<<<1, 64, 0, stream>>>(bsum, (NN + SCAN_BLK - 1) / SCAN_BLK);
  scan3_kernel<<<(NN + 255) / 256, 256, 0, stream>>>(offs, cursor, bsum, NN, NE);
  scatter_kernel<<<(NE + 255) / 256, 256, 0, stream>>>(edge_index, cursor, perm);

  edge_kernel<<<EDGE_BLOCKS, 256, 0, stream>>>(
      xbf, edge_attr, ubf, edge_index, batch,
      wE1t, wE2t, wE3t, eb1, eb2, eb3,
      edge_out, esumPart);

  partred_kernel<<<(EDGE_BLOCKS + PR_SPAN - 1) / PR_SPAN, 256, 0, stream>>>(esumPart, esum, EDGE_BLOCKS);

  agg_kernel<<<(NN * 64 + 255) / 256, 256, 0, stream>>>(edge_out, offs, perm, agg);

  node_kernel<<<NODE_BLOCKS, 256, 0, stream>>>(
      xbf, agg, x_out, ubf, batch,
      wN1t, wN2t, wN3t, nb1, nb2, nb3,
      nsumPart);

  partred_kernel<<<(NODE_BLOCKS + PR_SPAN - 1) / PR_SPAN, 256, 0, stream>>>(nsumPart, nsum, NODE_BLOCKS);

  global_kernel<<<1, 256, 0, stream>>>(
      u, nsum, ncnt, esum, ecnt,
      gW1, gb1, gW2, gb2, gW3, gb3, u_out);
}

// Round 12
// 560.528 us; speedup vs baseline: 2.0346x; 1.2239x over previous
//
#include <hip/hip_runtime.h>

#define NN 50000
#define NE 400000
#define NBATCH 8
#define DD 128

typedef unsigned short u16;
typedef __attribute__((ext_vector_type(8))) short bf16x8;
typedef __attribute__((ext_vector_type(8))) unsigned short u16x8;
typedef __attribute__((ext_vector_type(4))) unsigned short u16x4;
typedef __attribute__((ext_vector_type(4))) float f32x4;

__device__ __forceinline__ u16 f2bf(float f) {
  union { float f; unsigned u; } a; a.f = f;
  unsigned r = a.u + 0x7fffu + ((a.u >> 16) & 1u);
  return (u16)(r >> 16);
}

__device__ __forceinline__ void glds16(const void* g, void* l) {
  __builtin_amdgcn_global_load_lds(
      (const __attribute__((address_space(1))) unsigned*)g,
      (__attribute__((address_space(3))) unsigned*)l, 16, 0, 0);
}

// ---------------- merged prep kernel: all conversions + histograms + x_out zero ----------------
// block ranges:
//   [0,256)      wconv eW1 (K=512)     [256,320)  wconv eW2     [320,384) wconv eW3
//   [384,576)    wconv nW1 (K=384)     [576,640)  wconv nW2     [640,704) wconv nW3
//   [704,6954)   xconv x               [6954]     xconv u
//   [6955,7151)  nhist                 [7151,8714) ecnt
//   [8714,14964) zero x_out region (agg accumulator)
__global__ __launch_bounds__(256) void prep_kernel(
    const float* __restrict__ eW1, const float* __restrict__ eW2, const float* __restrict__ eW3,
    const float* __restrict__ nW1, const float* __restrict__ nW2, const float* __restrict__ nW3,
    u16* __restrict__ wE1t, u16* __restrict__ wE2t, u16* __restrict__ wE3t,
    u16* __restrict__ wN1t, u16* __restrict__ wN2t, u16* __restrict__ wN3t,
    const float* __restrict__ x, u16* __restrict__ xbf,
    const float* __restrict__ u, u16* __restrict__ ubf,
    const int* __restrict__ batch, unsigned* __restrict__ ncnt,
    const int* __restrict__ edge_index, unsigned* __restrict__ ecnt,
    float* __restrict__ xout_zero)
{
  const int b = blockIdx.x;
  const int tid = threadIdx.x;

  if (b < 704) {
    // weight convert+transpose
    const float* src; u16* dst; int K; int base;
    if (b < 256)      { src = eW1; dst = wE1t; K = 512; base = 0; }
    else if (b < 320) { src = eW2; dst = wE2t; K = 128; base = 256; }
    else if (b < 384) { src = eW3; dst = wE3t; K = 128; base = 320; }
    else if (b < 576) { src = nW1; dst = wN1t; K = 384; base = 384; }
    else if (b < 640) { src = nW2; dst = wN2t; K = 128; base = 576; }
    else              { src = nW3; dst = wN3t; K = 128; base = 640; }
    int idx = (b - base) * 256 + tid;
    if (idx < K * 128) {
      int k = idx >> 7, n = idx & 127;
      dst[((k >> 7) << 14) + (n << 7) + (k & 127)] = f2bf(src[idx]);
    }
    return;
  }
  if (b < 6954) {
    int i = (b - 704) * 256 + tid;   // < 1,600,000 exactly
    f32x4 v = ((const f32x4*)x)[i];
    u16x4 o; o[0]=f2bf(v[0]); o[1]=f2bf(v[1]); o[2]=f2bf(v[2]); o[3]=f2bf(v[3]);
    ((u16x4*)xbf)[i] = o;
    return;
  }
  if (b == 6954) {
    f32x4 v = ((const f32x4*)u)[tid];     // 256 == NBATCH*DD/4
    u16x4 o; o[0]=f2bf(v[0]); o[1]=f2bf(v[1]); o[2]=f2bf(v[2]); o[3]=f2bf(v[3]);
    ((u16x4*)ubf)[tid] = o;
    return;
  }
  if (b < 7151) {
    __shared__ unsigned h[NBATCH];
    if (tid < NBATCH) h[tid] = 0;
    __syncthreads();
    int i = (b - 6955) * 256 + tid;
    if (i < NN) atomicAdd(&h[batch[i]], 1u);
    __syncthreads();
    if (tid < NBATCH) atomicAdd(&ncnt[tid], h[tid]);
    return;
  }
  if (b < 8714) {
    __shared__ unsigned h[NBATCH];
    if (tid < NBATCH) h[tid] = 0;
    __syncthreads();
    int e = (b - 7151) * 256 + tid;
    if (e < NE) atomicAdd(&h[batch[edge_index[e]]], 1u);
    __syncthreads();
    if (tid < NBATCH) atomicAdd(&ecnt[tid], h[tid]);
    return;
  }
  {
    // zero x_out region: 6250 blocks x 1024 floats
    int i = (b - 8714) * 256 + tid;    // f32x4 index, < 1,600,000
    f32x4 z = {0.f, 0.f, 0.f, 0.f};
    ((f32x4*)xout_zero)[i] = z;
  }
}

// ---------- parallel partial reduce: [nslot][1024] -> out[1024] (atomic merge; out pre-zeroed) ----------
#define PR_SPAN 32
__global__ void partred_kernel(const float* __restrict__ part, float* __restrict__ out, int nslot) {
  int b0 = blockIdx.x * PR_SPAN;
  int i = threadIdx.x;
  int bend = b0 + PR_SPAN; if (bend > nslot) bend = nslot;
  float s0 = 0.f, s1 = 0.f, s2 = 0.f, s3 = 0.f;
  for (int b = b0; b < bend; ++b) {
    const float* p = part + (size_t)b * 1024;
    s0 += p[i]; s1 += p[256 + i]; s2 += p[512 + i]; s3 += p[768 + i];
  }
  atomicAdd(&out[i], s0);
  atomicAdd(&out[256 + i], s1);
  atomicAdd(&out[512 + i], s2);
  atomicAdd(&out[768 + i], s3);
}

// ---------------- Edge MLP: 64-edge tile, 32KB dbuf, 4 blk/CU ----------------
// R11 structure + agg scatter atomics (R10-measured ~free); esum via plain per-block stores.
__global__ __launch_bounds__(256, 4) void edge_kernel(
    const u16* __restrict__ xbf,
    const float* __restrict__ ea_f32, const u16* __restrict__ ubf,
    const int* __restrict__ edge_index, const int* __restrict__ batch,
    const u16* __restrict__ w1, const u16* __restrict__ w2, const u16* __restrict__ w3,
    const float* __restrict__ b1, const float* __restrict__ b2, const float* __restrict__ b3,
    float* __restrict__ edge_out, float* agg, float* __restrict__ esumPart)
{
  __shared__ u16 As[2][64 * 128];       // 32 KB double buffer
  __shared__ float red[NBATCH][128];
  __shared__ int rows_s[64], cols_s[64], ebat_s[64];

  const int tid  = threadIdx.x;
  const int lane = tid & 63;
  const int wave = tid >> 6;
  const int wc   = wave;                // 4 waves tile N=128 as 4 x 32 cols
  const int lr   = lane & 15;
  const int lkb  = lane >> 4;
  const int e0   = blockIdx.x * 64;

  if (tid < 64) {
    int r = edge_index[e0 + tid];
    int c = edge_index[NE + e0 + tid];
    rows_s[tid] = r; cols_s[tid] = c;
    ebat_s[tid] = batch[r];
  }
  for (int i = tid; i < NBATCH * 128; i += 256) (&red[0][0])[i] = 0.f;

  f32x4 acc[4][2];
#pragma unroll
  for (int m = 0; m < 4; ++m)
#pragma unroll
    for (int n = 0; n < 2; ++n) { acc[m][n][0]=0.f; acc[m][n][1]=0.f; acc[m][n][2]=0.f; acc[m][n][3]=0.f; }

  __syncthreads();  // indices visible

  auto stage = [&](int buf, int c) {
    if (c == 2) {
      // edge_attr fp32: reg-stage + cvt + swizzled ds_write (coalesced 512B/row)
#pragma unroll
      for (int j = 0; j < 4; ++j) {
        int idx = j * 64 + lane;
        int rr = wave * 16 + (idx >> 4);
        int k  = idx & 15;
        const float* p = ea_f32 + (size_t)(e0 + rr) * DD + k * 8;
        f32x4 a = *(const f32x4*)p;
        f32x4 b = *(const f32x4*)(p + 4);
        u16x8 v;
        v[0]=f2bf(a[0]); v[1]=f2bf(a[1]); v[2]=f2bf(a[2]); v[3]=f2bf(a[3]);
        v[4]=f2bf(b[0]); v[5]=f2bf(b[1]); v[6]=f2bf(b[2]); v[7]=f2bf(b[3]);
        *(u16x8*)&As[buf][rr * 128 + ((k ^ (rr & 7)) << 3)] = v;
      }
      return;
    }
#pragma unroll
    for (int i = 0; i < 4; ++i) {
      int rr = wave * 16 + i * 4 + (lane >> 4);
      const u16* rp;
      if (c == 0)      rp = xbf + (size_t)rows_s[rr] * DD;
      else if (c == 1) rp = xbf + (size_t)cols_s[rr] * DD;
      else             rp = ubf + (size_t)ebat_s[rr] * DD;
      const u16* src = rp + (((lane & 15) ^ (rr & 7)) << 3);  // inverse-swizzled source
      u16* dst = &As[buf][(wave * 16 + i * 4) * 128];         // linear wave-uniform dest
      glds16(src, dst);
    }
  };

  auto compute = [&](const u16* AsBuf, const u16* wsrc) {
#pragma unroll
    for (int kk = 0; kk < 4; ++kk) {
      const int k0 = kk * 32 + lkb * 8;
      bf16x8 af[4], bfv[2];
#pragma unroll
      for (int m = 0; m < 4; ++m) {
        int g = m * 16 + lr;
        int slot = kk * 4 + lkb;
        af[m] = *(const bf16x8*)(AsBuf + g * 128 + ((slot ^ (g & 7)) << 3));
      }
#pragma unroll
      for (int n = 0; n < 2; ++n)
        bfv[n] = *(const bf16x8*)(wsrc + ((wc * 32 + n * 16 + lr) << 7) + k0);
#pragma unroll
      for (int m = 0; m < 4; ++m)
#pragma unroll
        for (int n = 0; n < 2; ++n)
          acc[m][n] = __builtin_amdgcn_mfma_f32_16x16x32_bf16(af[m], bfv[n], acc[m][n], 0, 0, 0);
    }
  };

  auto epi_relu = [&](u16* HsBuf, const float* bias) {
#pragma unroll
    for (int n = 0; n < 2; ++n) {
      int colg = wc * 32 + n * 16 + lr;
      float bv = bias[colg];
      int slot = colg >> 3;
#pragma unroll
      for (int m = 0; m < 4; ++m)
#pragma unroll
        for (int r = 0; r < 4; ++r) {
          int rowg = m * 16 + lkb * 4 + r;
          float v = fmaxf(acc[m][n][r] + bv, 0.f);
          HsBuf[rowg * 128 + ((slot ^ (rowg & 7)) << 3) + (colg & 7)] = f2bf(v);
          acc[m][n][r] = 0.f;
        }
    }
  };

  // ---- layer 1: 4 chunks, 2-phase (stage next, compute current, barrier)
  stage(0, 0);
  __syncthreads();
  stage(1, 1); compute(As[0], w1);                __syncthreads();
  stage(0, 2); compute(As[1], w1 + (1 << 14));    __syncthreads();
  stage(1, 3); compute(As[0], w1 + (2 << 14));    __syncthreads();
               compute(As[1], w1 + (3 << 14));
  epi_relu(As[0], b1);
  __syncthreads();
  compute(As[0], w2);
  __syncthreads();
  epi_relu(As[1], b2);
  __syncthreads();
  compute(As[1], w3);

  // epilogue 3: edge_out stores + agg scatter atomics + per-graph red (LDS)
#pragma unroll
  for (int n = 0; n < 2; ++n) {
    int colg = wc * 32 + n * 16 + lr;
    float bias = b3[colg];
#pragma unroll
    for (int m = 0; m < 4; ++m)
#pragma unroll
      for (int r = 0; r < 4; ++r) {
        int rowg = m * 16 + lkb * 4 + r;
        float v = acc[m][n][r] + bias;
        edge_out[(size_t)(e0 + rowg) * DD + colg] = v;
        atomicAdd(&agg[(size_t)cols_s[rowg] * DD + colg], v);
        atomicAdd(&red[ebat_s[rowg]][colg], v);
      }
  }
  __syncthreads();
  // plain-store flush of per-block partial (no global atomics)
  for (int i = tid; i < NBATCH * 128; i += 256)
    esumPart[((size_t)blockIdx.x << 10) + i] = (&red[0][0])[i];
}

// ---------------- Node MLP: 64-node tile, agg read from x_out region, overwrite in place ----------------
__global__ __launch_bounds__(256, 4) void node_kernel(
    const u16* __restrict__ xbf, float* aggx /* agg in, x_out out (same region) */,
    const u16* __restrict__ ubf, const int* __restrict__ batch,
    const u16* __restrict__ w1, const u16* __restrict__ w2, const u16* __restrict__ w3,
    const float* __restrict__ b1, const float* __restrict__ b2, const float* __restrict__ b3,
    float* __restrict__ nsumPart)
{
  __shared__ u16 As[2][64 * 128];
  __shared__ float red[NBATCH][128];
  __shared__ int nbat_s[64];

  const int tid  = threadIdx.x;
  const int lane = tid & 63;
  const int wave = tid >> 6;
  const int wc   = wave;
  const int lr   = lane & 15;
  const int lkb  = lane >> 4;
  const int n0   = blockIdx.x * 64;

  if (tid < 64) {
    int node = n0 + tid;
    nbat_s[tid] = (node < NN) ? batch[node] : 0;
  }
  for (int i = tid; i < NBATCH * 128; i += 256) (&red[0][0])[i] = 0.f;

  f32x4 acc[4][2];
#pragma unroll
  for (int m = 0; m < 4; ++m)
#pragma unroll
    for (int n = 0; n < 2; ++n) { acc[m][n][0]=0.f; acc[m][n][1]=0.f; acc[m][n][2]=0.f; acc[m][n][3]=0.f; }

  __syncthreads();

  auto stage_bf = [&](int buf, int c) {   // c==0: xbf rows ; c==2: ubf rows
#pragma unroll
    for (int i = 0; i < 4; ++i) {
      int rr = wave * 16 + i * 4 + (lane >> 4);
      int node = n0 + rr; if (node >= NN) node = 0;
      const u16* rp = (c == 0) ? (xbf + (size_t)node * DD)
                               : (ubf + (size_t)nbat_s[rr] * DD);
      const u16* src = rp + (((lane & 15) ^ (rr & 7)) << 3);
      u16* dst = &As[buf][(wave * 16 + i * 4) * 128];
      glds16(src, dst);
    }
  };

  auto stage_agg = [&](int buf) {
#pragma unroll
    for (int j = 0; j < 4; ++j) {
      int idx = j * 64 + lane;
      int rr = wave * 16 + (idx >> 4);
      int k  = idx & 15;
      int node = n0 + rr; if (node >= NN) node = 0;
      const float* p = aggx + (size_t)node * DD + k * 8;
      f32x4 a = *(const f32x4*)p;
      f32x4 b = *(const f32x4*)(p + 4);
      u16x8 v;
      v[0]=f2bf(a[0]); v[1]=f2bf(a[1]); v[2]=f2bf(a[2]); v[3]=f2bf(a[3]);
      v[4]=f2bf(b[0]); v[5]=f2bf(b[1]); v[6]=f2bf(b[2]); v[7]=f2bf(b[3]);
      *(u16x8*)&As[buf][rr * 128 + ((k ^ (rr & 7)) << 3)] = v;
    }
  };

  auto compute = [&](const u16* AsBuf, const u16* wsrc) {
#pragma unroll
    for (int kk = 0; kk < 4; ++kk) {
      const int k0 = kk * 32 + lkb * 8;
      bf16x8 af[4], bfv[2];
#pragma unroll
      for (int m = 0; m < 4; ++m) {
        int g = m * 16 + lr;
        int slot = kk * 4 + lkb;
        af[m] = *(const bf16x8*)(AsBuf + g * 128 + ((slot ^ (g & 7)) << 3));
      }
#pragma unroll
      for (int n = 0; n < 2; ++n)
        bfv[n] = *(const bf16x8*)(wsrc + ((wc * 32 + n * 16 + lr) << 7) + k0);
#pragma unroll
      for (int m = 0; m < 4; ++m)
#pragma unroll
        for (int n = 0; n < 2; ++n)
          acc[m][n] = __builtin_amdgcn_mfma_f32_16x16x32_bf16(af[m], bfv[n], acc[m][n], 0, 0, 0);
    }
  };

  auto epi_relu = [&](u16* HsBuf, const float* bias) {
#pragma unroll
    for (int n = 0; n < 2; ++n) {
      int colg = wc * 32 + n * 16 + lr;
      float bv = bias[colg];
      int slot = colg >> 3;
#pragma unroll
      for (int m = 0; m < 4; ++m)
#pragma unroll
        for (int r = 0; r < 4; ++r) {
          int rowg = m * 16 + lkb * 4 + r;
          float v = fmaxf(acc[m][n][r] + bv, 0.f);
          HsBuf[rowg * 128 + ((slot ^ (rowg & 7)) << 3) + (colg & 7)] = f2bf(v);
          acc[m][n][r] = 0.f;
        }
    }
  };

  // layer 1: 3 chunks (x | agg | u), 2-phase
  stage_bf(0, 0);
  __syncthreads();
  stage_agg(1);   compute(As[0], w1);               __syncthreads();
  stage_bf(0, 2); compute(As[1], w1 + (1 << 14));   __syncthreads();
                  compute(As[0], w1 + (2 << 14));
  epi_relu(As[1], b1);
  __syncthreads();
  compute(As[1], w2);
  __syncthreads();
  epi_relu(As[0], b2);
  __syncthreads();
  compute(As[0], w3);

  // epilogue 3: x_out overwrites agg rows of this block; node-mean partials
#pragma unroll
  for (int n = 0; n < 2; ++n) {
    int colg = wc * 32 + n * 16 + lr;
    float bias = b3[colg];
#pragma unroll
    for (int m = 0; m < 4; ++m)
#pragma unroll
      for (int r = 0; r < 4; ++r) {
        int rowg = m * 16 + lkb * 4 + r;
        int node = n0 + rowg;
        if (node < NN) {
          float v = acc[m][n][r] + bias;
          aggx[(size_t)node * DD + colg] = v;
          atomicAdd(&red[nbat_s[rowg]][colg], v);
        }
      }
  }
  __syncthreads();
  for (int i = tid; i < NBATCH * 128; i += 256)
    nsumPart[((size_t)blockIdx.x << 10) + i] = (&red[0][0])[i];
}

// ---------------- Global MLP (fp32, tiny) ----------------
__global__ void global_kernel(
    const float* __restrict__ u,
    const float* __restrict__ nsum, const unsigned* __restrict__ ncnt,
    const float* __restrict__ esum, const unsigned* __restrict__ ecnt,
    const float* __restrict__ gW1, const float* __restrict__ gb1,
    const float* __restrict__ gW2, const float* __restrict__ gb2,
    const float* __restrict__ gW3, const float* __restrict__ gb3,
    float* __restrict__ u_out)
{
  __shared__ float gin[NBATCH][384];
  __shared__ float h1[NBATCH][128];
  __shared__ float h2[NBATCH][128];
  int tid = threadIdx.x;
  for (int i = tid; i < NBATCH * 128; i += 256) {
    int r = i >> 7, c = i & 127;
    float nc = (float)(ncnt[r] < 1u ? 1u : ncnt[r]);
    float ec = (float)(ecnt[r] < 1u ? 1u : ecnt[r]);
    gin[r][c] = u[i];
    gin[r][128 + c] = nsum[i] / nc;
    gin[r][256 + c] = esum[i] / ec;
  }
  __syncthreads();
  for (int o = tid; o < NBATCH * 128; o += 256) {
    int r = o >> 7, n = o & 127;
    float s = gb1[n];
    for (int k = 0; k < 384; ++k) s += gin[r][k] * gW1[k * 128 + n];
    h1[r][n] = fmaxf(s, 0.f);
  }
  __syncthreads();
  for (int o = tid; o < NBATCH * 128; o += 256) {
    int r = o >> 7, n = o & 127;
    float s = gb2[n];
    for (int k = 0; k < 128; ++k) s += h1[r][k] * gW2[k * 128 + n];
    h2[r][n] = fmaxf(s, 0.f);
  }
  __syncthreads();
  for (int o = tid; o < NBATCH * 128; o += 256) {
    int r = o >> 7, n = o & 127;
    float s = gb3[n];
    for (int k = 0; k < 128; ++k) s += h2[r][k] * gW3[k * 128 + n];
    u_out[o] = s;
  }
}

extern "C" void kernel_launch(void* const* d_in, const int* in_sizes, int n_in,
                              void* d_out, int out_size, void* d_ws, size_t ws_size,
                              hipStream_t stream) {
  const float* x          = (const float*)d_in[0];
  const int*   edge_index = (const int*)d_in[1];
  const float* edge_attr  = (const float*)d_in[2];
  const float* u          = (const float*)d_in[3];
  const int*   batch      = (const int*)d_in[4];
  const float* eW1 = (const float*)d_in[5];  const float* eb1 = (const float*)d_in[6];
  const float* eW2 = (const float*)d_in[7];  const float* eb2 = (const float*)d_in[8];
  const float* eW3 = (const float*)d_in[9];  const float* eb3 = (const float*)d_in[10];
  const float* nW1 = (const float*)d_in[11]; const float* nb1 = (const float*)d_in[12];
  const float* nW2 = (const float*)d_in[13]; const float* nb2 = (const float*)d_in[14];
  const float* nW3 = (const float*)d_in[15]; const float* nb3 = (const float*)d_in[16];
  const float* gW1 = (const float*)d_in[17]; const float* gb1 = (const float*)d_in[18];
  const float* gW2 = (const float*)d_in[19]; const float* gb2 = (const float*)d_in[20];
  const float* gW3 = (const float*)d_in[21]; const float* gb3 = (const float*)d_in[22];

  float* out      = (float*)d_out;
  float* xout_agg = out;                                  // [NN][128]: agg then x_out
  float* edge_out = out + (size_t)NN * DD;                // [NE][128]
  float* u_out    = out + (size_t)(NN + NE) * DD;         // [8][128]

  char* ws = (char*)d_ws;
  u16* wE1t = (u16*)(ws + 0);         // 131072
  u16* wE2t = (u16*)(ws + 131072);    // 32768
  u16* wE3t = (u16*)(ws + 163840);    // 32768
  u16* wN1t = (u16*)(ws + 196608);    // 98304
  u16* wN2t = (u16*)(ws + 294912);    // 32768
  u16* wN3t = (u16*)(ws + 327680);    // 32768
  float*    esum = (float*)(ws + 360448);     // 4096
  float*    nsum = (float*)(ws + 364544);     // 4096
  unsigned* ecnt = (unsigned*)(ws + 368640);  // 32
  unsigned* ncnt = (unsigned*)(ws + 368672);  // 32
  u16*      ubf  = (u16*)(ws + 369664);       // 2048
  u16*      xbf  = (u16*)(ws + 393216);       // 12,800,000 -> ends 13,193,216
  float* esumPart = (float*)(ws + 13193216);  // 6250*4096 = 25,600,000 -> 38,793,216
  float* nsumPart = (float*)(ws + 38793216);  // 782*4096  =  3,203,072 -> ends 41,996,288

  const int NODE_BLOCKS = (NN + 63) / 64;     // 782
  const int EDGE_BLOCKS = NE / 64;            // 6250

  // zero esum/nsum/ecnt/ncnt (must precede prep's histograms; separate dispatch for ordering)
  hipMemsetAsync(ws + 360448, 0, 8288, stream);

  prep_kernel<<<14964, 256, 0, stream>>>(
      eW1, eW2, eW3, nW1, nW2, nW3,
      wE1t, wE2t, wE3t, wN1t, wN2t, wN3t,
      x, xbf, u, ubf, batch, ncnt, edge_index, ecnt,
      xout_agg);

  edge_kernel<<<EDGE_BLOCKS, 256, 0, stream>>>(
      xbf, edge_attr, ubf, edge_index, batch,
      wE1t, wE2t, wE3t, eb1, eb2, eb3,
      edge_out, xout_agg, esumPart);

  partred_kernel<<<(EDGE_BLOCKS + PR_SPAN - 1) / PR_SPAN, 256, 0, stream>>>(esumPart, esum, EDGE_BLOCKS);

  node_kernel<<<NODE_BLOCKS, 256, 0, stream>>>(
      xbf, xout_agg, ubf, batch,
      wN1t, wN2t, wN3t, nb1, nb2, nb3,
      nsumPart);

  partred_kernel<<<(NODE_BLOCKS + PR_SPAN - 1) / PR_SPAN, 256, 0, stream>>>(nsumPart, nsum, NODE_BLOCKS);

  global_kernel<<<1, 256, 0, stream>>>(
      u, nsum, ncnt, esum, ecnt,
      gW1, gb1, gW2, gb2, gW3, gb3, u_out);
}